// Round 11
// baseline (636.970 us; speedup 1.0000x reference)
//
#include <hip/hip_runtime.h>
#include <hip/hip_bf16.h>
#include <math.h>

// Problem constants
#define NC 3
#define NK 64
#define KK 3
#define K2 9
#define PAD 1
#define SCALE 4
#define S2 16
#define MID 4
#define B 4
#define H 128
#define W 128
#define HW (H*W)          // 16384
#define CIN 67            // NK + NC
#define OUT_HW (H*SCALE)  // 512

typedef short bf16x8 __attribute__((ext_vector_type(8)));
typedef float f32x4 __attribute__((ext_vector_type(4)));

__device__ __forceinline__ float fast_sigmoid(float v) { return 1.f / (1.f + __expf(-v)); }
__device__ __forceinline__ float fast_tanh(float v) { return 2.f / (1.f + __expf(-2.f * v)) - 1.f; }

// fp32 -> bf16 round-to-nearest-even
__device__ __forceinline__ unsigned short f2bf(float f) {
    unsigned int u = __float_as_uint(f);
    unsigned int r = (u + 0x7FFFu + ((u >> 16) & 1u)) >> 16;
    return (unsigned short)r;
}

// load a zero-padded 3x3 patch of one channel plane (HxW) at (y,x)
__device__ __forceinline__ void load_patch(const float* __restrict__ xc, int y, int x, float* p) {
#pragma unroll
    for (int dy = -1; dy <= 1; dy++) {
#pragma unroll
        for (int dx = -1; dx <= 1; dx++) {
            int yy = y + dy, xx = x + dx;
            float v = (yy >= 0 && yy < H && xx >= 0 && xx < W) ? xc[yy * W + xx] : 0.f;
            p[(dy + 1) * 3 + (dx + 1)] = v;
        }
    }
}

// ---------------------------------------------------------------------------
// ConvLSTM with h=0,c=0: only first NC input channels of lstm_w matter;
// f-gate irrelevant (c_prev=0). blockIdx.y selects a 16-channel gate group.
// ---------------------------------------------------------------------------
__global__ __launch_bounds__(256) void k_lstm(const float* __restrict__ X,
                                              const float* __restrict__ lw,
                                              const float* __restrict__ lb,
                                              float* __restrict__ xcatA,
                                              float* __restrict__ hid_out,
                                              float* __restrict__ cell_out) {
    int t = blockIdx.x * blockDim.x + threadIdx.x;
    int b = t >> 14, hw = t & (HW - 1), y = hw >> 7, x = hw & (W - 1);
    int nk0 = blockIdx.y * 16;
    float p[NC][9];
#pragma unroll
    for (int c = 0; c < NC; c++) load_patch(X + (b * NC + c) * HW, y, x, p[c]);
    float* xc = xcatA + (size_t)b * CIN * HW;
    for (int i = 0; i < 16; i++) {
        int nk = nk0 + i;
        float gi = lb[nk], go = lb[2 * NK + nk], gg = lb[3 * NK + nk];
#pragma unroll
        for (int c = 0; c < NC; c++) {
            const float* wi = lw + (size_t)(nk) * (CIN * 9) + c * 9;
            const float* wo = lw + (size_t)(2 * NK + nk) * (CIN * 9) + c * 9;
            const float* wg = lw + (size_t)(3 * NK + nk) * (CIN * 9) + c * 9;
#pragma unroll
            for (int tt = 0; tt < 9; tt++) {
                gi += p[c][tt] * wi[tt];
                go += p[c][tt] * wo[tt];
                gg += p[c][tt] * wg[tt];
            }
        }
        float cv = fast_sigmoid(gi) * fast_tanh(gg);
        float hv = fast_sigmoid(go) * fast_tanh(cv);
        xc[nk * HW + hw] = hv;
        hid_out[(b * NK + nk) * HW + hw] = hv;
        cell_out[(b * NK + nk) * HW + hw] = cv;
    }
}

// copy lr (X) into channels 64..66 of both xcat buffers
__global__ __launch_bounds__(256) void k_copy_lr(const float* __restrict__ X,
                                                 float* __restrict__ xcatA,
                                                 float* __restrict__ xcatB) {
    int t = blockIdx.x * blockDim.x + threadIdx.x;
    int b = t >> 14, hw = t & (HW - 1);
#pragma unroll
    for (int c = 0; c < NC; c++) {
        float v = X[(b * NC + c) * HW + hw];
        xcatA[(size_t)b * CIN * HW + (NK + c) * HW + hw] = v;
        xcatB[(size_t)b * CIN * HW + (NK + c) * HW + hw] = v;
    }
}

// ---------------------------------------------------------------------------
// Prepack deform weights dw[o<64][c<67][k<9] into MFMA A-fragment order, bf16:
// frag g = (tap*3+ks)*4+mt: apk[g*512 + lane*8 + j] = A[m][kc] with
// m = mt*16+(lane&15), kc = ks*32+(lane>>4)*8+j (per-tap channel; 0 if >=67).
// grid 108 blocks x 512 threads.
// ---------------------------------------------------------------------------
__global__ void k_prepA(const float* __restrict__ w, unsigned short* __restrict__ apk) {
    int g = blockIdx.x;            // (tap*3+ks)*4+mt
    int tid = threadIdx.x;         // 0..511
    int lane = tid >> 3, j = tid & 7;
    int mt = g & 3, r = g >> 2;    // r = tap*3+ks
    int ks = r % 3, tap = r / 3;
    int o = mt * 16 + (lane & 15);
    int c = ks * 32 + ((lane >> 4) << 3) + j;
    float val = (c < CIN) ? w[(size_t)o * (CIN * 9) + c * 9 + tap] : 0.f;
    apk[(size_t)g * 512 + tid] = f2bf(val);
}

// ---------------------------------------------------------------------------
// Prepack offset(18)+mask(9) conv weights into M=32 A-fragments, bf16:
// frag g = (tap*3+kss)*2+mt: o = mt*16+(lane&15) (o<18 -> ow row, 18..26 ->
// mw row o-18, else 0), c = kss*32+(lane>>4)*8+j (0 if >=67).
// grid 54 x 512.
// ---------------------------------------------------------------------------
__global__ void k_prepOM(const float* __restrict__ ow, const float* __restrict__ mw,
                         unsigned short* __restrict__ apk) {
    int g = blockIdx.x;            // (tap*3+kss)*2+mt
    int tid = threadIdx.x;         // 0..511
    int lane = tid >> 3, j = tid & 7;
    int mt = g & 1, r = g >> 1;    // r = tap*3+kss
    int kss = r % 3, tap = r / 3;
    int o = mt * 16 + (lane & 15);
    int c = kss * 32 + ((lane >> 4) << 3) + j;
    float val = 0.f;
    if (c < CIN) {
        if (o < 18) val = ow[(size_t)o * (CIN * 9) + c * 9 + tap];
        else if (o < 27) val = mw[(size_t)(o - 18) * (CIN * 9) + c * 9 + tap];
    }
    apk[(size_t)g * 512 + tid] = f2bf(val);
}

// ---------------------------------------------------------------------------
// Offset + mask convs as MFMA implicit GEMM. Block = 256 thr = 4 waves =
// 64 px strip; wave nt owns 16 px (N-tile). Per tap: regular (zero-padded)
// patch sample per lane; per kss a register B-frag (8 channel loads) and
// 2 MFMAs vs prepacked A (M=32 covers 27 outputs). Epilogue writes PACKED
// per-pixel float4 (offy,offx,2*sigmoid(mask),pad) at omp[(b*HW+hw)*9+tap]
// so deform reads one dwordx4 per (lane,tap). Barrier/LDS-free. XCD swizzle.
// ---------------------------------------------------------------------------
__global__ __launch_bounds__(256) void k_offmask(const float* __restrict__ xcat,
                                                 const unsigned short* __restrict__ apk,
                                                 const float* __restrict__ ob,
                                                 const float* __restrict__ mb,
                                                 float* __restrict__ omp) {
    int tid = threadIdx.x;
    int lane = tid & 63;
    int nt = __builtin_amdgcn_readfirstlane(tid >> 6);
    int blk = blockIdx.x;
    int sg = (blk & 7) * 128 + (blk >> 3);  // XCD-contiguous strip id
    int b = sg >> 8;
    int hwbase = (sg & 255) * 64;
    int n = lane & 15, q = lane >> 4;
    int hw = hwbase + nt * 16 + n;
    int y = hw >> 7, x = hw & (W - 1);

    f32x4 acc[2];
#pragma unroll
    for (int mt = 0; mt < 2; mt++) { f32x4 z = {0.f, 0.f, 0.f, 0.f}; acc[mt] = z; }

    const float* xb = xcat + (size_t)b * CIN * HW;
#pragma unroll 1
    for (int tap = 0; tap < K2; tap++) {
        int ky = tap / 3, kx = tap - ky * 3;
        int yy = y + ky - 1, xx = x + kx - 1;
        float valid = (yy >= 0 && yy < H && xx >= 0 && xx < W) ? 1.f : 0.f;
        int ii = min(max(yy, 0), H - 1) * W + min(max(xx, 0), W - 1);
        const unsigned short* ab = apk + (size_t)(tap * 6) * 512 + lane * 8;
#pragma unroll
        for (int kss = 0; kss < 3; kss++) {
            bf16x8 bf;
#pragma unroll
            for (int j = 0; j < 8; j++) {
                int c = kss * 32 + q * 8 + j;
                float v = 0.f;
                if (c < CIN) v = xb[(size_t)c * HW + ii] * valid;
                bf[j] = (short)f2bf(v);
            }
#pragma unroll
            for (int mt = 0; mt < 2; mt++) {
                bf16x8 af = *(const bf16x8*)(ab + (size_t)(kss * 2 + mt) * 512);
                acc[mt] = __builtin_amdgcn_mfma_f32_16x16x32_bf16(af, bf, acc[mt], 0, 0, 0);
            }
        }
    }

    // epilogue: D[row=q*4+r][col=n]; o<18: offset plane o = 2*tap+(y/x);
    // o in [18,27): mask tap o-18. Packed: omp[(b*HW+hw)*9+tap] = {oy,ox,m,_}
    float* base = omp + ((size_t)b * HW + hw) * 36;
#pragma unroll
    for (int mt = 0; mt < 2; mt++) {
#pragma unroll
        for (int r = 0; r < 4; r++) {
            int o = mt * 16 + q * 4 + r;
            float v = acc[mt][r];
            if (o < 18) {
                int tap = o >> 1, slot = o & 1;
                base[tap * 4 + slot] = v + ob[o];
            } else if (o < 27) {
                int tap = o - 18;
                base[tap * 4 + 2] = 2.f * fast_sigmoid(v + mb[tap]);
            }
        }
    }
}

// ---------------------------------------------------------------------------
// Deformable conv as fused implicit GEMM, split-K x2. Block = 256 thr =
// 32 px strip; wave = (N-tile nt2 in {0,1}) x (K-half kh: taps 0-4 / 5-8).
// Per tap: ONE dwordx4 read of packed (offy,offx,m) -> bilinear coefs for
// this lane's pixel; register B-frags (8 channel gathers each); 4 MFMAs vs
// prepacked A. unroll 2 on taps for cross-tap ILP (packed loads have no
// inter-tap deps). kh=1 partials via LDS (17-pad), single barrier. XCD swz.
// ---------------------------------------------------------------------------
__global__ __launch_bounds__(256) void k_deform(const float* __restrict__ xcat,
                                                const float* __restrict__ omp,
                                                const unsigned short* __restrict__ apk,
                                                const float* __restrict__ bias,
                                                float* __restrict__ xout) {
    __shared__ float red[2 * 64 * 17];  // 8704 B
    int tid = threadIdx.x;
    int lane = tid & 63;
    int wid = __builtin_amdgcn_readfirstlane(tid >> 6);
    int nt2 = wid & 1, kh = wid >> 1;
    int blk = blockIdx.x;                    // 0..2047
    int sg = (blk & 7) * 256 + (blk >> 3);   // XCD-contiguous strip id
    int b = sg >> 9;
    int hwbase = (sg & 511) * 32;
    int n = lane & 15, q = lane >> 4;
    int hw = hwbase + nt2 * 16 + n;
    int y = hw >> 7, x = hw & (W - 1);

    f32x4 acc[4];
#pragma unroll
    for (int mt = 0; mt < 4; mt++) { f32x4 z = {0.f, 0.f, 0.f, 0.f}; acc[mt] = z; }

    const float* xb = xcat + (size_t)b * CIN * HW;
    const float4* ompx = (const float4*)(omp + ((size_t)b * HW + hw) * 36);
    int t0 = kh ? 5 : 0, t1 = kh ? 9 : 5;
#pragma unroll 2
    for (int tap = t0; tap < t1; tap++) {
        // packed per-pixel (offy, offx, mask) — one aligned dwordx4
        float4 om = ompx[tap];
        int ky = tap / 3, kx = tap - ky * 3;
        float py = (float)(y + ky - 1) + om.x;
        float px_ = (float)(x + kx - 1) + om.y;
        float m = om.z;
        float fy = floorf(py), fx = floorf(px_);
        float wy = py - fy, wx = px_ - fx;
        int y0 = (int)fy, x0 = (int)fx;
        int y1 = y0 + 1, x1 = x0 + 1;
        float vy0 = (y0 >= 0 && y0 <= H - 1) ? 1.f : 0.f;
        float vy1 = (y1 >= 0 && y1 <= H - 1) ? 1.f : 0.f;
        float vx0 = (x0 >= 0 && x0 <= W - 1) ? 1.f : 0.f;
        float vx1 = (x1 >= 0 && x1 <= W - 1) ? 1.f : 0.f;
        int yc0 = min(max(y0, 0), H - 1), yc1 = min(max(y1, 0), H - 1);
        int xc0 = min(max(x0, 0), W - 1), xc1 = min(max(x1, 0), W - 1);
        float a00 = (1.f - wy) * (1.f - wx) * m * vy0 * vx0;
        float a01 = (1.f - wy) * wx * m * vy0 * vx1;
        float a10 = wy * (1.f - wx) * m * vy1 * vx0;
        float a11 = wy * wx * m * vy1 * vx1;
        int j00 = yc0 * W + xc0, j01 = yc0 * W + xc1;
        int j10 = yc1 * W + xc0, j11 = yc1 * W + xc1;

        const unsigned short* ab = apk + (size_t)(tap * 12) * 512 + lane * 8;
#pragma unroll
        for (int ks = 0; ks < 3; ks++) {
            bf16x8 bf;
#pragma unroll
            for (int j = 0; j < 8; j++) {
                int c = ks * 32 + q * 8 + j;
                float v = 0.f;
                if (c < CIN) {
                    const float* xc = xb + c * HW;
                    v = a00 * xc[j00] + a01 * xc[j01] + a10 * xc[j10] + a11 * xc[j11];
                }
                bf[j] = (short)f2bf(v);
            }
#pragma unroll
            for (int mt = 0; mt < 4; mt++) {
                bf16x8 af = *(const bf16x8*)(ab + (size_t)(ks * 4 + mt) * 512);
                acc[mt] = __builtin_amdgcn_mfma_f32_16x16x32_bf16(af, bf, acc[mt], 0, 0, 0);
            }
        }
    }

    // split-K reduction: kh=1 waves stage partials, kh=0 waves add + store
    if (kh) {
#pragma unroll
        for (int mt = 0; mt < 4; mt++) {
#pragma unroll
            for (int r = 0; r < 4; r++) {
                int o = mt * 16 + q * 4 + r;
                red[(nt2 * 64 + o) * 17 + n] = acc[mt][r];
            }
        }
    }
    __syncthreads();
    if (!kh) {
        float* xo = xout + (size_t)b * CIN * HW + hwbase + nt2 * 16 + n;
#pragma unroll
        for (int mt = 0; mt < 4; mt++) {
#pragma unroll
            for (int r = 0; r < 4; r++) {
                int o = mt * 16 + q * 4 + r;
                xo[(size_t)o * HW] = acc[mt][r] + red[(nt2 * 64 + o) * 17 + n] + bias[o];
            }
        }
    }
}

// final 3-channel conv over 67-channel concat; single pass computes all 3
// outputs (patch loads not duplicated across output channels)
__global__ __launch_bounds__(256) void k_conv3(const float* __restrict__ xcat,
                                               const float* __restrict__ cw,
                                               const float* __restrict__ cb,
                                               float* __restrict__ y3) {
    int t = blockIdx.x * blockDim.x + threadIdx.x;
    int b = t >> 14, hw = t & (HW - 1), y = hw >> 7, x = hw & (W - 1);
    float acc[NC] = {cb[0], cb[1], cb[2]};
    const float* xb = xcat + (size_t)b * CIN * HW;
    for (int c = 0; c < CIN; c++) {
        float p[9];
        load_patch(xb + c * HW, y, x, p);
#pragma unroll
        for (int oc = 0; oc < NC; oc++) {
            const float* w = cw + (size_t)oc * (CIN * 9) + c * 9;
#pragma unroll
            for (int tt = 0; tt < 9; tt++) acc[oc] += p[tt] * w[tt];
        }
    }
#pragma unroll
    for (int oc = 0; oc < NC; oc++) y3[(b * NC + oc) * HW + hw] = acc[oc];
}

// global average pool: one block per (b,c)
__global__ __launch_bounds__(256) void k_pool(const float* __restrict__ y3,
                                              float* __restrict__ pooled) {
    int bc = blockIdx.x;  // 0..11
    const float* p = y3 + (size_t)bc * HW;
    float s = 0.f;
    for (int i = threadIdx.x; i < HW; i += 256) s += p[i];
    __shared__ float red[256];
    red[threadIdx.x] = s;
    __syncthreads();
    for (int off = 128; off > 0; off >>= 1) {
        if (threadIdx.x < off) red[threadIdx.x] += red[threadIdx.x + off];
        __syncthreads();
    }
    if (threadIdx.x == 0) pooled[bc] = red[0] / (float)HW;
}

// tiny per-branch channel MLP -> ch[b,s,c,k]
__global__ void k_ch(const float* __restrict__ pooled, const float* __restrict__ w1,
                     const float* __restrict__ b1, const float* __restrict__ w2,
                     const float* __restrict__ b2, float* __restrict__ chbuf) {
    int t = threadIdx.x;
    if (t >= B * S2) return;
    int b = t >> 4, s = t & 15;
    float h1[MID];
#pragma unroll
    for (int m = 0; m < MID; m++) {
        float a = b1[s * MID + m];
#pragma unroll
        for (int c = 0; c < NC; c++) a += pooled[b * NC + c] * w1[(s * MID + m) * NC + c];
        h1[m] = fmaxf(a, 0.f);
    }
    for (int kk = 0; kk < NC * K2; kk++) {
        float a = b2[s * (NC * K2) + kk];
#pragma unroll
        for (int m = 0; m < MID; m++) a += h1[m] * w2[(s * (NC * K2) + kk) * MID + m];
        chbuf[(b * S2 + s) * (NC * K2) + kk] = a;
    }
}

// ---------------------------------------------------------------------------
// Fused DDF upsample: spatial-filter conv + dynamic combine + pixel_shuffle
// + clip. blockIdx.y selects 4 of the 16 branches; that quarter of sp_w/sp_b
// and ch staged in LDS (block is single-batch).
// ---------------------------------------------------------------------------
__global__ __launch_bounds__(256) void k_ddf(const float* __restrict__ y3,
                                             const float* __restrict__ spw,
                                             const float* __restrict__ spb,
                                             const float* __restrict__ chbuf,
                                             float* __restrict__ out) {
    __shared__ float s_spw[4 * K2 * NC * 9];  // 972
    __shared__ float s_spb[4 * K2];           // 36
    __shared__ float s_ch[4 * NC * K2];       // 108
    int t = blockIdx.x * blockDim.x + threadIdx.x;
    int b = t >> 14, hw = t & (HW - 1), y = hw >> 7, x = hw & (W - 1);
    int s0 = blockIdx.y * 4;
    for (int i = threadIdx.x; i < 4 * K2 * NC * 9; i += 256) s_spw[i] = spw[s0 * K2 * NC * 9 + i];
    if (threadIdx.x < 4 * K2) s_spb[threadIdx.x] = spb[s0 * K2 + threadIdx.x];
    if (threadIdx.x < 4 * NC * K2) s_ch[threadIdx.x] = chbuf[b * (S2 * NC * K2) + s0 * NC * K2 + threadIdx.x];
    __syncthreads();
    float p[NC][9];
#pragma unroll
    for (int c = 0; c < NC; c++) load_patch(y3 + (b * NC + c) * HW, y, x, p[c]);
#pragma unroll
    for (int si = 0; si < 4; si++) {
        int s = s0 + si;
        float spv[K2];
#pragma unroll
        for (int k = 0; k < K2; k++) {
            float a = s_spb[si * K2 + k];
            const float* w = s_spw + (si * K2 + k) * (NC * 9);
#pragma unroll
            for (int c = 0; c < NC; c++)
#pragma unroll
                for (int tt = 0; tt < 9; tt++) a += p[c][tt] * w[c * 9 + tt];
            spv[k] = a;
        }
        int sy = s >> 2, sx = s & 3;
#pragma unroll
        for (int c = 0; c < NC; c++) {
            float a = 0.f;
            const float* chp = s_ch + (si * NC + c) * K2;
#pragma unroll
            for (int k = 0; k < K2; k++) a += p[c][k] * (chp[k] + spv[k]);
            a = fminf(fmaxf(a, 0.f), 255.f);
            out[((size_t)(b * NC + c) * OUT_HW + (y * SCALE + sy)) * OUT_HW + (x * SCALE + sx)] = a;
        }
    }
}

extern "C" void kernel_launch(void* const* d_in, const int* in_sizes, int n_in,
                              void* d_out, int out_size, void* d_ws, size_t ws_size,
                              hipStream_t stream) {
    const float* X = (const float*)d_in[0];
    const float* lstm_w = (const float*)d_in[1];
    const float* lstm_b = (const float*)d_in[2];
    const float* ow[3] = {(const float*)d_in[3], (const float*)d_in[9], (const float*)d_in[15]};
    const float* ob[3] = {(const float*)d_in[4], (const float*)d_in[10], (const float*)d_in[16]};
    const float* mw[3] = {(const float*)d_in[5], (const float*)d_in[11], (const float*)d_in[17]};
    const float* mb[3] = {(const float*)d_in[6], (const float*)d_in[12], (const float*)d_in[18]};
    const float* dw[3] = {(const float*)d_in[7], (const float*)d_in[13], (const float*)d_in[19]};
    const float* db[3] = {(const float*)d_in[8], (const float*)d_in[14], (const float*)d_in[20]};
    const float* conv_w = (const float*)d_in[21];
    const float* conv_b = (const float*)d_in[22];
    const float* sp_w = (const float*)d_in[23];
    const float* sp_b = (const float*)d_in[24];
    const float* ch_w1 = (const float*)d_in[25];
    const float* ch_b1 = (const float*)d_in[26];
    const float* ch_w2 = (const float*)d_in[27];
    const float* ch_b2 = (const float*)d_in[28];

    float* out = (float*)d_out;
    const size_t OUT_IMG = (size_t)B * NC * OUT_HW * OUT_HW;  // 3145728
    const size_t HIDSZ = (size_t)B * NK * HW;                 // 4194304
    float* hid_out = out + OUT_IMG;
    float* cell_out = out + OUT_IMG + HIDSZ;

    float* ws = (float*)d_ws;
    const size_t XCAT = (size_t)B * CIN * HW;  // 4390912
    float* xcatA = ws;            ws += XCAT;
    float* xcatB = ws;            ws += XCAT;
    float* omp = ws;              ws += (size_t)B * HW * 36;   // packed off/mask
    unsigned short* apk[3];
    for (int i = 0; i < 3; i++) { apk[i] = (unsigned short*)ws; ws += 108 * 512 / 2; }
    unsigned short* apkOM[3];
    for (int i = 0; i < 3; i++) { apkOM[i] = (unsigned short*)ws; ws += 54 * 512 / 2; }
    float* y3 = ws;               ws += (size_t)B * NC * HW;
    float* pooled = ws;           ws += 16;
    float* chbuf = ws;            ws += (size_t)B * S2 * NC * K2;

    dim3 blk(256);
    dim3 g1(B * HW / 256);        // 256 blocks
    dim3 g4(B * HW / 256, 4);
    dim3 gd(B * HW / 64);         // 1024 strips (offmask)
    dim3 gd2(B * HW / 32);        // 2048 strips (split-K deform)

    k_lstm<<<g4, blk, 0, stream>>>(X, lstm_w, lstm_b, xcatA, hid_out, cell_out);
    k_copy_lr<<<g1, blk, 0, stream>>>(X, xcatA, xcatB);
    for (int i = 0; i < 3; i++) {
        k_prepA<<<dim3(108), dim3(512), 0, stream>>>(dw[i], apk[i]);
        k_prepOM<<<dim3(54), dim3(512), 0, stream>>>(ow[i], mw[i], apkOM[i]);
    }

    // layer 1: xcatA -> xcatB
    k_offmask<<<gd, blk, 0, stream>>>(xcatA, apkOM[0], ob[0], mb[0], omp);
    k_deform<<<gd2, blk, 0, stream>>>(xcatA, omp, apk[0], db[0], xcatB);
    // layer 2: xcatB -> xcatA
    k_offmask<<<gd, blk, 0, stream>>>(xcatB, apkOM[1], ob[1], mb[1], omp);
    k_deform<<<gd2, blk, 0, stream>>>(xcatB, omp, apk[1], db[1], xcatA);
    // layer 3: xcatA -> xcatB
    k_offmask<<<gd, blk, 0, stream>>>(xcatA, apkOM[2], ob[2], mb[2], omp);
    k_deform<<<gd2, blk, 0, stream>>>(xcatA, omp, apk[2], db[2], xcatB);

    k_conv3<<<g1, blk, 0, stream>>>(xcatB, conv_w, conv_b, y3);
    k_pool<<<dim3(B * NC), blk, 0, stream>>>(y3, pooled);
    k_ch<<<dim3(1), dim3(64), 0, stream>>>(pooled, ch_w1, ch_b1, ch_w2, ch_b2, chbuf);
    k_ddf<<<g4, blk, 0, stream>>>(y3, sp_w, sp_b, chbuf, out);
}

// Round 12
// 564.842 us; speedup vs baseline: 1.1277x; 1.1277x over previous
//
#include <hip/hip_runtime.h>
#include <hip/hip_bf16.h>
#include <math.h>

// Problem constants
#define NC 3
#define NK 64
#define KK 3
#define K2 9
#define PAD 1
#define SCALE 4
#define S2 16
#define MID 4
#define B 4
#define H 128
#define W 128
#define HW (H*W)          // 16384
#define CIN 67            // NK + NC
#define OUT_HW (H*SCALE)  // 512
#define CST 64            // pixel-major xcat row: 64 floats (256 B)

typedef short bf16x8 __attribute__((ext_vector_type(8)));
typedef float f32x4 __attribute__((ext_vector_type(4)));

__device__ __forceinline__ float fast_sigmoid(float v) { return 1.f / (1.f + __expf(-v)); }
__device__ __forceinline__ float fast_tanh(float v) { return 2.f / (1.f + __expf(-2.f * v)) - 1.f; }

// fp32 -> bf16 round-to-nearest-even
__device__ __forceinline__ unsigned short f2bf(float f) {
    unsigned int u = __float_as_uint(f);
    unsigned int r = (u + 0x7FFFu + ((u >> 16) & 1u)) >> 16;
    return (unsigned short)r;
}

// load a zero-padded 3x3 patch of one channel plane (HxW) at (y,x)
__device__ __forceinline__ void load_patch(const float* __restrict__ xc, int y, int x, float* p) {
#pragma unroll
    for (int dy = -1; dy <= 1; dy++) {
#pragma unroll
        for (int dx = -1; dx <= 1; dx++) {
            int yy = y + dy, xx = x + dx;
            float v = (yy >= 0 && yy < H && xx >= 0 && xx < W) ? xc[yy * W + xx] : 0.f;
            p[(dy + 1) * 3 + (dx + 1)] = v;
        }
    }
}

// ---------------------------------------------------------------------------
// ConvLSTM with h=0,c=0. Writes hid channels into PIXEL-MAJOR xcatA rows
// (vector float4 stores) + hid/cell to d_out (channel-major, harness layout).
// blockIdx.y = 16-channel gate group.
// ---------------------------------------------------------------------------
__global__ __launch_bounds__(256) void k_lstm(const float* __restrict__ X,
                                              const float* __restrict__ lw,
                                              const float* __restrict__ lb,
                                              float* __restrict__ xcatA,
                                              float* __restrict__ hid_out,
                                              float* __restrict__ cell_out) {
    int t = blockIdx.x * blockDim.x + threadIdx.x;
    int b = t >> 14, hw = t & (HW - 1), y = hw >> 7, x = hw & (W - 1);
    int nk0 = blockIdx.y * 16;
    float p[NC][9];
#pragma unroll
    for (int c = 0; c < NC; c++) load_patch(X + (b * NC + c) * HW, y, x, p[c]);
    float hv16[16];
#pragma unroll
    for (int i = 0; i < 16; i++) {
        int nk = nk0 + i;
        float gi = lb[nk], go = lb[2 * NK + nk], gg = lb[3 * NK + nk];
#pragma unroll
        for (int c = 0; c < NC; c++) {
            const float* wi = lw + (size_t)(nk) * (CIN * 9) + c * 9;
            const float* wo = lw + (size_t)(2 * NK + nk) * (CIN * 9) + c * 9;
            const float* wg = lw + (size_t)(3 * NK + nk) * (CIN * 9) + c * 9;
#pragma unroll
            for (int tt = 0; tt < 9; tt++) {
                gi += p[c][tt] * wi[tt];
                go += p[c][tt] * wo[tt];
                gg += p[c][tt] * wg[tt];
            }
        }
        float cv = fast_sigmoid(gi) * fast_tanh(gg);
        float hv = fast_sigmoid(go) * fast_tanh(cv);
        hv16[i] = hv;
        hid_out[(b * NK + nk) * HW + hw] = hv;
        cell_out[(b * NK + nk) * HW + hw] = cv;
    }
    float* row = xcatA + ((size_t)b * HW + hw) * CST + nk0;
#pragma unroll
    for (int g = 0; g < 4; g++) {
        f32x4 v = {hv16[4 * g], hv16[4 * g + 1], hv16[4 * g + 2], hv16[4 * g + 3]};
        *(f32x4*)(row + 4 * g) = v;
    }
}

// lr channels pixel-major: lrp[(b*HW+hw)*4] = {X0, X1, X2, 0}
__global__ __launch_bounds__(256) void k_lr(const float* __restrict__ X,
                                            float* __restrict__ lrp) {
    int t = blockIdx.x * blockDim.x + threadIdx.x;
    int b = t >> 14, hw = t & (HW - 1);
    f32x4 v = {X[(b * NC + 0) * HW + hw], X[(b * NC + 1) * HW + hw],
               X[(b * NC + 2) * HW + hw], 0.f};
    *(f32x4*)(lrp + ((size_t)b * HW + hw) * 4) = v;
}

// ---------------------------------------------------------------------------
// Prepack deform weights dw[o<64][c<67][k<9] into MFMA A-fragment order, bf16:
// frag g = (tap*3+ks)*4+mt: apk[g*512 + lane*8 + j] = A[m][kc] with
// m = mt*16+(lane&15), kc = ks*32+(lane>>4)*8+j (per-tap channel; 0 if >=67).
// ---------------------------------------------------------------------------
__global__ void k_prepA(const float* __restrict__ w, unsigned short* __restrict__ apk) {
    int g = blockIdx.x;            // (tap*3+ks)*4+mt
    int tid = threadIdx.x;         // 0..511
    int lane = tid >> 3, j = tid & 7;
    int mt = g & 3, r = g >> 2;    // r = tap*3+ks
    int ks = r % 3, tap = r / 3;
    int o = mt * 16 + (lane & 15);
    int c = ks * 32 + ((lane >> 4) << 3) + j;
    float val = (c < CIN) ? w[(size_t)o * (CIN * 9) + c * 9 + tap] : 0.f;
    apk[(size_t)g * 512 + tid] = f2bf(val);
}

// Prepack offset(18)+mask(9) conv weights into M=32 A-fragments, bf16.
__global__ void k_prepOM(const float* __restrict__ ow, const float* __restrict__ mw,
                         unsigned short* __restrict__ apk) {
    int g = blockIdx.x;            // (tap*3+kss)*2+mt
    int tid = threadIdx.x;         // 0..511
    int lane = tid >> 3, j = tid & 7;
    int mt = g & 1, r = g >> 1;    // r = tap*3+kss
    int kss = r % 3, tap = r / 3;
    int o = mt * 16 + (lane & 15);
    int c = kss * 32 + ((lane >> 4) << 3) + j;
    float val = 0.f;
    if (c < CIN) {
        if (o < 18) val = ow[(size_t)o * (CIN * 9) + c * 9 + tap];
        else if (o < 27) val = mw[(size_t)(o - 18) * (CIN * 9) + c * 9 + tap];
    }
    apk[(size_t)g * 512 + tid] = f2bf(val);
}

// ---------------------------------------------------------------------------
// Offset + mask convs as MFMA implicit GEMM over PIXEL-MAJOR xcat. Per tap:
// clamped patch pixel ii; kss 0/1 -> two dwordx4 vector loads of 8 channels;
// kss 2 -> q==0 lanes load lrp float4 (c 64..67). Epilogue writes packed
// per-pixel float4 (offy,offx,2*sigmoid(mask),pad). Barrier/LDS-free.
// ---------------------------------------------------------------------------
__global__ __launch_bounds__(256) void k_offmask(const float* __restrict__ xcat,
                                                 const float* __restrict__ lrp,
                                                 const unsigned short* __restrict__ apk,
                                                 const float* __restrict__ ob,
                                                 const float* __restrict__ mb,
                                                 float* __restrict__ omp) {
    int tid = threadIdx.x;
    int lane = tid & 63;
    int nt = __builtin_amdgcn_readfirstlane(tid >> 6);
    int blk = blockIdx.x;
    int sg = (blk & 7) * 128 + (blk >> 3);  // XCD-contiguous strip id
    int b = sg >> 8;
    int hwbase = (sg & 255) * 64;
    int n = lane & 15, q = lane >> 4;
    int hw = hwbase + nt * 16 + n;
    int y = hw >> 7, x = hw & (W - 1);

    f32x4 acc[2];
#pragma unroll
    for (int mt = 0; mt < 2; mt++) { f32x4 z = {0.f, 0.f, 0.f, 0.f}; acc[mt] = z; }

    const float* xb = xcat + (size_t)b * HW * CST;
    const float* lb_ = lrp + (size_t)b * HW * 4;
#pragma unroll 1
    for (int tap = 0; tap < K2; tap++) {
        int ky = tap / 3, kx = tap - ky * 3;
        int yy = y + ky - 1, xx = x + kx - 1;
        float valid = (yy >= 0 && yy < H && xx >= 0 && xx < W) ? 1.f : 0.f;
        int ii = min(max(yy, 0), H - 1) * W + min(max(xx, 0), W - 1);
        const float* xr = xb + ((size_t)ii << 6);
        const unsigned short* ab = apk + (size_t)(tap * 6) * 512 + lane * 8;
#pragma unroll
        for (int kss = 0; kss < 2; kss++) {
            int c0 = kss * 32 + q * 8;
            f32x4 va = *(const f32x4*)(xr + c0);
            f32x4 vb = *(const f32x4*)(xr + c0 + 4);
            bf16x8 bf;
#pragma unroll
            for (int j = 0; j < 4; j++) bf[j] = (short)f2bf(va[j] * valid);
#pragma unroll
            for (int j = 0; j < 4; j++) bf[4 + j] = (short)f2bf(vb[j] * valid);
#pragma unroll
            for (int mt = 0; mt < 2; mt++) {
                bf16x8 af = *(const bf16x8*)(ab + (size_t)(kss * 2 + mt) * 512);
                acc[mt] = __builtin_amdgcn_mfma_f32_16x16x32_bf16(af, bf, acc[mt], 0, 0, 0);
            }
        }
        // kss = 2: lr channels (c 64..66) carried by q==0 lanes only
        bf16x8 bf2 = {0, 0, 0, 0, 0, 0, 0, 0};
        if (q == 0) {
            f32x4 L = *(const f32x4*)(lb_ + ((size_t)ii << 2));
#pragma unroll
            for (int j = 0; j < 4; j++) bf2[j] = (short)f2bf(L[j] * valid);
        }
#pragma unroll
        for (int mt = 0; mt < 2; mt++) {
            bf16x8 af = *(const bf16x8*)(ab + (size_t)(2 * 2 + mt) * 512);
            acc[mt] = __builtin_amdgcn_mfma_f32_16x16x32_bf16(af, bf2, acc[mt], 0, 0, 0);
        }
    }

    // epilogue: D[row=q*4+r][col=n]; packed omp[(b*HW+hw)*9+tap] = {oy,ox,m,_}
    float* base = omp + ((size_t)b * HW + hw) * 36;
#pragma unroll
    for (int mt = 0; mt < 2; mt++) {
#pragma unroll
        for (int r = 0; r < 4; r++) {
            int o = mt * 16 + q * 4 + r;
            float v = acc[mt][r];
            if (o < 18) {
                int tap = o >> 1, slot = o & 1;
                base[tap * 4 + slot] = v + ob[o];
            } else if (o < 27) {
                int tap = o - 18;
                base[tap * 4 + 2] = 2.f * fast_sigmoid(v + mb[tap]);
            }
        }
    }
}

// ---------------------------------------------------------------------------
// Deformable conv as fused implicit GEMM over PIXEL-MAJOR xcat, split-K x2.
// Block = 256 thr = 32 px strip; wave = (N-tile nt2) x (K-half kh: taps
// 0-4 / 5-8). Per tap: one dwordx4 packed (offy,offx,m); 4 corner row
// pointers; ks 0/1 -> 8 dwordx4 vector loads (4 corners x 8 ch), fp32
// bilinear combine, pack; ks 2 -> q==0 lanes bilinear of lrp float4s.
// 4 MFMAs per ks vs prepacked A. kh=1 partials via LDS, single barrier.
// Epilogue: float4 stores into pixel rows. XCD strip swizzle.
// ---------------------------------------------------------------------------
__global__ __launch_bounds__(256) void k_deform(const float* __restrict__ xcat,
                                                const float* __restrict__ lrp,
                                                const float* __restrict__ omp,
                                                const unsigned short* __restrict__ apk,
                                                const float* __restrict__ bias,
                                                float* __restrict__ xout) {
    __shared__ float red[2 * 64 * 17];  // 8704 B
    int tid = threadIdx.x;
    int lane = tid & 63;
    int wid = __builtin_amdgcn_readfirstlane(tid >> 6);
    int nt2 = wid & 1, kh = wid >> 1;
    int blk = blockIdx.x;                    // 0..2047
    int sg = (blk & 7) * 256 + (blk >> 3);   // XCD-contiguous strip id
    int b = sg >> 9;
    int hwbase = (sg & 511) * 32;
    int n = lane & 15, q = lane >> 4;
    int hw = hwbase + nt2 * 16 + n;
    int y = hw >> 7, x = hw & (W - 1);

    f32x4 acc[4];
#pragma unroll
    for (int mt = 0; mt < 4; mt++) { f32x4 z = {0.f, 0.f, 0.f, 0.f}; acc[mt] = z; }

    const float* xb = xcat + (size_t)b * HW * CST;
    const float* lb_ = lrp + (size_t)b * HW * 4;
    const f32x4* ompx = (const f32x4*)(omp + ((size_t)b * HW + hw) * 36);
    int t0 = kh ? 5 : 0, t1 = kh ? 9 : 5;
#pragma unroll 1
    for (int tap = t0; tap < t1; tap++) {
        f32x4 om = ompx[tap];
        int ky = tap / 3, kx = tap - ky * 3;
        float py = (float)(y + ky - 1) + om[0];
        float px_ = (float)(x + kx - 1) + om[1];
        float m = om[2];
        float fy = floorf(py), fx = floorf(px_);
        float wy = py - fy, wx = px_ - fx;
        int y0 = (int)fy, x0 = (int)fx;
        int y1 = y0 + 1, x1 = x0 + 1;
        float vy0 = (y0 >= 0 && y0 <= H - 1) ? 1.f : 0.f;
        float vy1 = (y1 >= 0 && y1 <= H - 1) ? 1.f : 0.f;
        float vx0 = (x0 >= 0 && x0 <= W - 1) ? 1.f : 0.f;
        float vx1 = (x1 >= 0 && x1 <= W - 1) ? 1.f : 0.f;
        int yc0 = min(max(y0, 0), H - 1), yc1 = min(max(y1, 0), H - 1);
        int xc0 = min(max(x0, 0), W - 1), xc1 = min(max(x1, 0), W - 1);
        float a00 = (1.f - wy) * (1.f - wx) * m * vy0 * vx0;
        float a01 = (1.f - wy) * wx * m * vy0 * vx1;
        float a10 = wy * (1.f - wx) * m * vy1 * vx0;
        float a11 = wy * wx * m * vy1 * vx1;
        int j00 = yc0 * W + xc0, j01 = yc0 * W + xc1;
        int j10 = yc1 * W + xc0, j11 = yc1 * W + xc1;

        const float* r00 = xb + ((size_t)j00 << 6);
        const float* r01 = xb + ((size_t)j01 << 6);
        const float* r10 = xb + ((size_t)j10 << 6);
        const float* r11 = xb + ((size_t)j11 << 6);
        const unsigned short* ab = apk + (size_t)(tap * 12) * 512 + lane * 8;
#pragma unroll
        for (int ks = 0; ks < 2; ks++) {
            int c0 = ks * 32 + q * 8;
            f32x4 u00 = *(const f32x4*)(r00 + c0), v00 = *(const f32x4*)(r00 + c0 + 4);
            f32x4 u01 = *(const f32x4*)(r01 + c0), v01 = *(const f32x4*)(r01 + c0 + 4);
            f32x4 u10 = *(const f32x4*)(r10 + c0), v10 = *(const f32x4*)(r10 + c0 + 4);
            f32x4 u11 = *(const f32x4*)(r11 + c0), v11 = *(const f32x4*)(r11 + c0 + 4);
            bf16x8 bf;
#pragma unroll
            for (int j = 0; j < 4; j++) {
                float v = a00 * u00[j] + a01 * u01[j] + a10 * u10[j] + a11 * u11[j];
                bf[j] = (short)f2bf(v);
            }
#pragma unroll
            for (int j = 0; j < 4; j++) {
                float v = a00 * v00[j] + a01 * v01[j] + a10 * v10[j] + a11 * v11[j];
                bf[4 + j] = (short)f2bf(v);
            }
#pragma unroll
            for (int mt = 0; mt < 4; mt++) {
                bf16x8 af = *(const bf16x8*)(ab + (size_t)(ks * 4 + mt) * 512);
                acc[mt] = __builtin_amdgcn_mfma_f32_16x16x32_bf16(af, bf, acc[mt], 0, 0, 0);
            }
        }
        // ks = 2: lr channels via q==0 lanes (c 64..67; rest zero, A zero too)
        bf16x8 bf2 = {0, 0, 0, 0, 0, 0, 0, 0};
        if (q == 0) {
            f32x4 L00 = *(const f32x4*)(lb_ + ((size_t)j00 << 2));
            f32x4 L01 = *(const f32x4*)(lb_ + ((size_t)j01 << 2));
            f32x4 L10 = *(const f32x4*)(lb_ + ((size_t)j10 << 2));
            f32x4 L11 = *(const f32x4*)(lb_ + ((size_t)j11 << 2));
#pragma unroll
            for (int j = 0; j < 4; j++) {
                float v = a00 * L00[j] + a01 * L01[j] + a10 * L10[j] + a11 * L11[j];
                bf2[j] = (short)f2bf(v);
            }
        }
#pragma unroll
        for (int mt = 0; mt < 4; mt++) {
            bf16x8 af = *(const bf16x8*)(ab + (size_t)(2 * 4 + mt) * 512);
            acc[mt] = __builtin_amdgcn_mfma_f32_16x16x32_bf16(af, bf2, acc[mt], 0, 0, 0);
        }
    }

    // split-K reduction: kh=1 waves stage partials, kh=0 waves add + store
    if (kh) {
#pragma unroll
        for (int mt = 0; mt < 4; mt++) {
#pragma unroll
            for (int r = 0; r < 4; r++) {
                int o = mt * 16 + q * 4 + r;
                red[(nt2 * 64 + o) * 17 + n] = acc[mt][r];
            }
        }
    }
    __syncthreads();
    if (!kh) {
        float* xo = xout + ((size_t)b * HW + hw) * CST;
#pragma unroll
        for (int mt = 0; mt < 4; mt++) {
            f32x4 st;
#pragma unroll
            for (int r = 0; r < 4; r++) {
                int o = mt * 16 + q * 4 + r;
                st[r] = acc[mt][r] + red[(nt2 * 64 + o) * 17 + n] + bias[o];
            }
            *(f32x4*)(xo + mt * 16 + q * 4) = st;
        }
    }
}

// final 3-channel conv over pixel-major xcat (64 ch) + lrp (3 ch)
__global__ __launch_bounds__(256) void k_conv3(const float* __restrict__ xcat,
                                               const float* __restrict__ lrp,
                                               const float* __restrict__ cw,
                                               const float* __restrict__ cb,
                                               float* __restrict__ y3) {
    int t = blockIdx.x * blockDim.x + threadIdx.x;
    int b = t >> 14, hw = t & (HW - 1), y = hw >> 7, x = hw & (W - 1);
    float acc[NC] = {cb[0], cb[1], cb[2]};
    const float* xb = xcat + (size_t)b * HW * CST;
    const float* lb_ = lrp + (size_t)b * HW * 4;
#pragma unroll 1
    for (int tap = 0; tap < K2; tap++) {
        int ky = tap / 3, kx = tap - ky * 3;
        int yy = y + ky - 1, xx = x + kx - 1;
        if (yy < 0 || yy >= H || xx < 0 || xx >= W) continue;
        int ii = yy * W + xx;
        const f32x4* xr = (const f32x4*)(xb + ((size_t)ii << 6));
#pragma unroll
        for (int c4 = 0; c4 < 16; c4++) {
            f32x4 v = xr[c4];
#pragma unroll
            for (int e = 0; e < 4; e++) {
                int c = c4 * 4 + e;
#pragma unroll
                for (int oc = 0; oc < NC; oc++)
                    acc[oc] += v[e] * cw[(size_t)oc * (CIN * 9) + c * 9 + tap];
            }
        }
        f32x4 L = *(const f32x4*)(lb_ + ((size_t)ii << 2));
#pragma unroll
        for (int e = 0; e < 3; e++)
#pragma unroll
            for (int oc = 0; oc < NC; oc++)
                acc[oc] += L[e] * cw[(size_t)oc * (CIN * 9) + (64 + e) * 9 + tap];
    }
#pragma unroll
    for (int oc = 0; oc < NC; oc++) y3[(b * NC + oc) * HW + hw] = acc[oc];
}

// global average pool: one block per (b,c)
__global__ __launch_bounds__(256) void k_pool(const float* __restrict__ y3,
                                              float* __restrict__ pooled) {
    int bc = blockIdx.x;  // 0..11
    const float* p = y3 + (size_t)bc * HW;
    float s = 0.f;
    for (int i = threadIdx.x; i < HW; i += 256) s += p[i];
    __shared__ float red[256];
    red[threadIdx.x] = s;
    __syncthreads();
    for (int off = 128; off > 0; off >>= 1) {
        if (threadIdx.x < off) red[threadIdx.x] += red[threadIdx.x + off];
        __syncthreads();
    }
    if (threadIdx.x == 0) pooled[bc] = red[0] / (float)HW;
}

// tiny per-branch channel MLP -> ch[b,s,c,k]
__global__ void k_ch(const float* __restrict__ pooled, const float* __restrict__ w1,
                     const float* __restrict__ b1, const float* __restrict__ w2,
                     const float* __restrict__ b2, float* __restrict__ chbuf) {
    int t = threadIdx.x;
    if (t >= B * S2) return;
    int b = t >> 4, s = t & 15;
    float h1[MID];
#pragma unroll
    for (int m = 0; m < MID; m++) {
        float a = b1[s * MID + m];
#pragma unroll
        for (int c = 0; c < NC; c++) a += pooled[b * NC + c] * w1[(s * MID + m) * NC + c];
        h1[m] = fmaxf(a, 0.f);
    }
    for (int kk = 0; kk < NC * K2; kk++) {
        float a = b2[s * (NC * K2) + kk];
#pragma unroll
        for (int m = 0; m < MID; m++) a += h1[m] * w2[(s * (NC * K2) + kk) * MID + m];
        chbuf[(b * S2 + s) * (NC * K2) + kk] = a;
    }
}

// ---------------------------------------------------------------------------
// Fused DDF upsample: spatial-filter conv + dynamic combine + pixel_shuffle
// + clip. blockIdx.y selects 4 of the 16 branches; that quarter of sp_w/sp_b
// and ch staged in LDS (block is single-batch).
// ---------------------------------------------------------------------------
__global__ __launch_bounds__(256) void k_ddf(const float* __restrict__ y3,
                                             const float* __restrict__ spw,
                                             const float* __restrict__ spb,
                                             const float* __restrict__ chbuf,
                                             float* __restrict__ out) {
    __shared__ float s_spw[4 * K2 * NC * 9];  // 972
    __shared__ float s_spb[4 * K2];           // 36
    __shared__ float s_ch[4 * NC * K2];       // 108
    int t = blockIdx.x * blockDim.x + threadIdx.x;
    int b = t >> 14, hw = t & (HW - 1), y = hw >> 7, x = hw & (W - 1);
    int s0 = blockIdx.y * 4;
    for (int i = threadIdx.x; i < 4 * K2 * NC * 9; i += 256) s_spw[i] = spw[s0 * K2 * NC * 9 + i];
    if (threadIdx.x < 4 * K2) s_spb[threadIdx.x] = spb[s0 * K2 + threadIdx.x];
    if (threadIdx.x < 4 * NC * K2) s_ch[threadIdx.x] = chbuf[b * (S2 * NC * K2) + s0 * NC * K2 + threadIdx.x];
    __syncthreads();
    float p[NC][9];
#pragma unroll
    for (int c = 0; c < NC; c++) load_patch(y3 + (b * NC + c) * HW, y, x, p[c]);
#pragma unroll
    for (int si = 0; si < 4; si++) {
        int s = s0 + si;
        float spv[K2];
#pragma unroll
        for (int k = 0; k < K2; k++) {
            float a = s_spb[si * K2 + k];
            const float* w = s_spw + (si * K2 + k) * (NC * 9);
#pragma unroll
            for (int c = 0; c < NC; c++)
#pragma unroll
                for (int tt = 0; tt < 9; tt++) a += p[c][tt] * w[c * 9 + tt];
            spv[k] = a;
        }
        int sy = s >> 2, sx = s & 3;
#pragma unroll
        for (int c = 0; c < NC; c++) {
            float a = 0.f;
            const float* chp = s_ch + (si * NC + c) * K2;
#pragma unroll
            for (int k = 0; k < K2; k++) a += p[c][k] * (chp[k] + spv[k]);
            a = fminf(fmaxf(a, 0.f), 255.f);
            out[((size_t)(b * NC + c) * OUT_HW + (y * SCALE + sy)) * OUT_HW + (x * SCALE + sx)] = a;
        }
    }
}

extern "C" void kernel_launch(void* const* d_in, const int* in_sizes, int n_in,
                              void* d_out, int out_size, void* d_ws, size_t ws_size,
                              hipStream_t stream) {
    const float* X = (const float*)d_in[0];
    const float* lstm_w = (const float*)d_in[1];
    const float* lstm_b = (const float*)d_in[2];
    const float* ow[3] = {(const float*)d_in[3], (const float*)d_in[9], (const float*)d_in[15]};
    const float* ob[3] = {(const float*)d_in[4], (const float*)d_in[10], (const float*)d_in[16]};
    const float* mw[3] = {(const float*)d_in[5], (const float*)d_in[11], (const float*)d_in[17]};
    const float* mb[3] = {(const float*)d_in[6], (const float*)d_in[12], (const float*)d_in[18]};
    const float* dw[3] = {(const float*)d_in[7], (const float*)d_in[13], (const float*)d_in[19]};
    const float* db[3] = {(const float*)d_in[8], (const float*)d_in[14], (const float*)d_in[20]};
    const float* conv_w = (const float*)d_in[21];
    const float* conv_b = (const float*)d_in[22];
    const float* sp_w = (const float*)d_in[23];
    const float* sp_b = (const float*)d_in[24];
    const float* ch_w1 = (const float*)d_in[25];
    const float* ch_b1 = (const float*)d_in[26];
    const float* ch_w2 = (const float*)d_in[27];
    const float* ch_b2 = (const float*)d_in[28];

    float* out = (float*)d_out;
    const size_t OUT_IMG = (size_t)B * NC * OUT_HW * OUT_HW;  // 3145728
    const size_t HIDSZ = (size_t)B * NK * HW;                 // 4194304
    float* hid_out = out + OUT_IMG;
    float* cell_out = out + OUT_IMG + HIDSZ;

    float* ws = (float*)d_ws;
    const size_t XCAT = (size_t)B * HW * CST;  // 4.19M floats, pixel-major
    float* xcatA = ws;            ws += XCAT;
    float* xcatB = ws;            ws += XCAT;
    float* lrp = ws;              ws += (size_t)B * HW * 4;
    float* omp = ws;              ws += (size_t)B * HW * 36;   // packed off/mask
    unsigned short* apk[3];
    for (int i = 0; i < 3; i++) { apk[i] = (unsigned short*)ws; ws += 108 * 512 / 2; }
    unsigned short* apkOM[3];
    for (int i = 0; i < 3; i++) { apkOM[i] = (unsigned short*)ws; ws += 54 * 512 / 2; }
    float* y3 = ws;               ws += (size_t)B * NC * HW;
    float* pooled = ws;           ws += 16;
    float* chbuf = ws;            ws += (size_t)B * S2 * NC * K2;

    dim3 blk(256);
    dim3 g1(B * HW / 256);        // 256 blocks
    dim3 g4(B * HW / 256, 4);
    dim3 gd(B * HW / 64);         // 1024 strips (offmask)
    dim3 gd2(B * HW / 32);        // 2048 strips (split-K deform)

    k_lstm<<<g4, blk, 0, stream>>>(X, lstm_w, lstm_b, xcatA, hid_out, cell_out);
    k_lr<<<g1, blk, 0, stream>>>(X, lrp);
    for (int i = 0; i < 3; i++) {
        k_prepA<<<dim3(108), dim3(512), 0, stream>>>(dw[i], apk[i]);
        k_prepOM<<<dim3(54), dim3(512), 0, stream>>>(ow[i], mw[i], apkOM[i]);
    }

    // layer 1: xcatA -> xcatB
    k_offmask<<<gd, blk, 0, stream>>>(xcatA, lrp, apkOM[0], ob[0], mb[0], omp);
    k_deform<<<gd2, blk, 0, stream>>>(xcatA, lrp, omp, apk[0], db[0], xcatB);
    // layer 2: xcatB -> xcatA
    k_offmask<<<gd, blk, 0, stream>>>(xcatB, lrp, apkOM[1], ob[1], mb[1], omp);
    k_deform<<<gd2, blk, 0, stream>>>(xcatB, lrp, omp, apk[1], db[1], xcatA);
    // layer 3: xcatA -> xcatB
    k_offmask<<<gd, blk, 0, stream>>>(xcatA, lrp, apkOM[2], ob[2], mb[2], omp);
    k_deform<<<gd2, blk, 0, stream>>>(xcatA, lrp, omp, apk[2], db[2], xcatB);

    k_conv3<<<g1, blk, 0, stream>>>(xcatB, lrp, conv_w, conv_b, y3);
    k_pool<<<dim3(B * NC), blk, 0, stream>>>(y3, pooled);
    k_ch<<<dim3(1), dim3(64), 0, stream>>>(pooled, ch_w1, ch_b1, ch_w2, ch_b2, chbuf);
    k_ddf<<<g4, blk, 0, stream>>>(y3, sp_w, sp_b, chbuf, out);
}

// Round 13
// 516.055 us; speedup vs baseline: 1.2343x; 1.0945x over previous
//
#include <hip/hip_runtime.h>
#include <hip/hip_bf16.h>
#include <math.h>

// Problem constants
#define NC 3
#define NK 64
#define KK 3
#define K2 9
#define PAD 1
#define SCALE 4
#define S2 16
#define MID 4
#define B 4
#define H 128
#define W 128
#define HW (H*W)          // 16384
#define CIN 67            // NK + NC
#define OUT_HW (H*SCALE)  // 512
#define CST 64            // pixel-major xcat row: 64 bf16 (128 B)

typedef short bf16x8 __attribute__((ext_vector_type(8)));
typedef float f32x4 __attribute__((ext_vector_type(4)));
typedef unsigned int u32x4 __attribute__((ext_vector_type(4)));
typedef unsigned int u32x2 __attribute__((ext_vector_type(2)));

__device__ __forceinline__ float fast_sigmoid(float v) { return 1.f / (1.f + __expf(-v)); }
__device__ __forceinline__ float fast_tanh(float v) { return 2.f / (1.f + __expf(-2.f * v)) - 1.f; }

// fp32 -> bf16 round-to-nearest-even
__device__ __forceinline__ unsigned short f2bf(float f) {
    unsigned int u = __float_as_uint(f);
    unsigned int r = (u + 0x7FFFu + ((u >> 16) & 1u)) >> 16;
    return (unsigned short)r;
}

// load a zero-padded 3x3 patch of one channel plane (HxW) at (y,x)
__device__ __forceinline__ void load_patch(const float* __restrict__ xc, int y, int x, float* p) {
#pragma unroll
    for (int dy = -1; dy <= 1; dy++) {
#pragma unroll
        for (int dx = -1; dx <= 1; dx++) {
            int yy = y + dy, xx = x + dx;
            float v = (yy >= 0 && yy < H && xx >= 0 && xx < W) ? xc[yy * W + xx] : 0.f;
            p[(dy + 1) * 3 + (dx + 1)] = v;
        }
    }
}

// ---------------------------------------------------------------------------
// ConvLSTM with h=0,c=0. Writes hid channels into PIXEL-MAJOR bf16 xcatA rows
// + hid/cell to d_out (channel-major fp32, harness layout).
// ---------------------------------------------------------------------------
__global__ __launch_bounds__(256) void k_lstm(const float* __restrict__ X,
                                              const float* __restrict__ lw,
                                              const float* __restrict__ lb,
                                              unsigned short* __restrict__ xcatA,
                                              float* __restrict__ hid_out,
                                              float* __restrict__ cell_out) {
    int t = blockIdx.x * blockDim.x + threadIdx.x;
    int b = t >> 14, hw = t & (HW - 1), y = hw >> 7, x = hw & (W - 1);
    int nk0 = blockIdx.y * 16;
    float p[NC][9];
#pragma unroll
    for (int c = 0; c < NC; c++) load_patch(X + (b * NC + c) * HW, y, x, p[c]);
    float hv16[16];
#pragma unroll
    for (int i = 0; i < 16; i++) {
        int nk = nk0 + i;
        float gi = lb[nk], go = lb[2 * NK + nk], gg = lb[3 * NK + nk];
#pragma unroll
        for (int c = 0; c < NC; c++) {
            const float* wi = lw + (size_t)(nk) * (CIN * 9) + c * 9;
            const float* wo = lw + (size_t)(2 * NK + nk) * (CIN * 9) + c * 9;
            const float* wg = lw + (size_t)(3 * NK + nk) * (CIN * 9) + c * 9;
#pragma unroll
            for (int tt = 0; tt < 9; tt++) {
                gi += p[c][tt] * wi[tt];
                go += p[c][tt] * wo[tt];
                gg += p[c][tt] * wg[tt];
            }
        }
        float cv = fast_sigmoid(gi) * fast_tanh(gg);
        float hv = fast_sigmoid(go) * fast_tanh(cv);
        hv16[i] = hv;
        hid_out[(b * NK + nk) * HW + hw] = hv;
        cell_out[(b * NK + nk) * HW + hw] = cv;
    }
    unsigned short* row = xcatA + ((size_t)b * HW + hw) * CST + nk0;
#pragma unroll
    for (int g = 0; g < 4; g++) {
        u32x2 st;
        st[0] = (unsigned int)f2bf(hv16[4 * g]) | ((unsigned int)f2bf(hv16[4 * g + 1]) << 16);
        st[1] = (unsigned int)f2bf(hv16[4 * g + 2]) | ((unsigned int)f2bf(hv16[4 * g + 3]) << 16);
        *(u32x2*)(row + 4 * g) = st;
    }
}

// lr channels pixel-major: lrp[(b*HW+hw)*4] = {X0, X1, X2, 0}
__global__ __launch_bounds__(256) void k_lr(const float* __restrict__ X,
                                            float* __restrict__ lrp) {
    int t = blockIdx.x * blockDim.x + threadIdx.x;
    int b = t >> 14, hw = t & (HW - 1);
    f32x4 v = {X[(b * NC + 0) * HW + hw], X[(b * NC + 1) * HW + hw],
               X[(b * NC + 2) * HW + hw], 0.f};
    *(f32x4*)(lrp + ((size_t)b * HW + hw) * 4) = v;
}

// ---------------------------------------------------------------------------
// Prepack deform weights dw[o<64][c<67][k<9] into MFMA A-fragment order, bf16:
// frag g = (tap*3+ks)*4+mt: apk[g*512 + lane*8 + j] = A[m][kc] with
// m = mt*16+(lane&15), kc = ks*32+(lane>>4)*8+j (per-tap channel; 0 if >=67).
// ---------------------------------------------------------------------------
__global__ void k_prepA(const float* __restrict__ w, unsigned short* __restrict__ apk) {
    int g = blockIdx.x;            // (tap*3+ks)*4+mt
    int tid = threadIdx.x;         // 0..511
    int lane = tid >> 3, j = tid & 7;
    int mt = g & 3, r = g >> 2;    // r = tap*3+ks
    int ks = r % 3, tap = r / 3;
    int o = mt * 16 + (lane & 15);
    int c = ks * 32 + ((lane >> 4) << 3) + j;
    float val = (c < CIN) ? w[(size_t)o * (CIN * 9) + c * 9 + tap] : 0.f;
    apk[(size_t)g * 512 + tid] = f2bf(val);
}

// Prepack offset(18)+mask(9) conv weights into M=32 A-fragments, bf16.
__global__ void k_prepOM(const float* __restrict__ ow, const float* __restrict__ mw,
                         unsigned short* __restrict__ apk) {
    int g = blockIdx.x;            // (tap*3+kss)*2+mt
    int tid = threadIdx.x;         // 0..511
    int lane = tid >> 3, j = tid & 7;
    int mt = g & 1, r = g >> 1;    // r = tap*3+kss
    int kss = r % 3, tap = r / 3;
    int o = mt * 16 + (lane & 15);
    int c = kss * 32 + ((lane >> 4) << 3) + j;
    float val = 0.f;
    if (c < CIN) {
        if (o < 18) val = ow[(size_t)o * (CIN * 9) + c * 9 + tap];
        else if (o < 27) val = mw[(size_t)(o - 18) * (CIN * 9) + c * 9 + tap];
    }
    apk[(size_t)g * 512 + tid] = f2bf(val);
}

// ---------------------------------------------------------------------------
// Offset + mask convs as MFMA implicit GEMM over PIXEL-MAJOR bf16 xcat.
// Per tap (FULLY UNROLLED - all loads independent & hoistable): clamped patch
// pixel ii; kss 0/1 -> one bf16x8 load each (direct B-frag, zeroed if
// invalid); kss 2 -> q==0 lanes pack lrp float4. Epilogue: packed per-pixel
// float4 (offy,offx,2*sigmoid(mask),pad). Barrier/LDS-free. XCD swizzle.
// ---------------------------------------------------------------------------
__global__ __launch_bounds__(256, 4) void k_offmask(const unsigned short* __restrict__ xcat,
                                                    const float* __restrict__ lrp,
                                                    const unsigned short* __restrict__ apk,
                                                    const float* __restrict__ ob,
                                                    const float* __restrict__ mb,
                                                    float* __restrict__ omp) {
    int tid = threadIdx.x;
    int lane = tid & 63;
    int nt = __builtin_amdgcn_readfirstlane(tid >> 6);
    int blk = blockIdx.x;
    int sg = (blk & 7) * 128 + (blk >> 3);  // XCD-contiguous strip id
    int b = sg >> 8;
    int hwbase = (sg & 255) * 64;
    int n = lane & 15, q = lane >> 4;
    int hw = hwbase + nt * 16 + n;
    int y = hw >> 7, x = hw & (W - 1);

    f32x4 acc[2];
#pragma unroll
    for (int mt = 0; mt < 2; mt++) { f32x4 z = {0.f, 0.f, 0.f, 0.f}; acc[mt] = z; }

    const unsigned short* xb = xcat + (size_t)b * HW * CST;
    const float* lb_ = lrp + (size_t)b * HW * 4;
#pragma unroll
    for (int tap = 0; tap < K2; tap++) {
        int ky = tap / 3, kx = tap - ky * 3;
        int yy = y + ky - 1, xx = x + kx - 1;
        bool vld = (yy >= 0 && yy < H && xx >= 0 && xx < W);
        int ii = min(max(yy, 0), H - 1) * W + min(max(xx, 0), W - 1);
        const unsigned short* xr = xb + ((size_t)ii << 6);
        const unsigned short* ab = apk + (size_t)(tap * 6) * 512 + lane * 8;
#pragma unroll
        for (int kss = 0; kss < 2; kss++) {
            bf16x8 bfv = *(const bf16x8*)(xr + kss * 32 + q * 8);
            if (!vld) { bf16x8 z = {0, 0, 0, 0, 0, 0, 0, 0}; bfv = z; }
#pragma unroll
            for (int mt = 0; mt < 2; mt++) {
                bf16x8 af = *(const bf16x8*)(ab + (size_t)(kss * 2 + mt) * 512);
                acc[mt] = __builtin_amdgcn_mfma_f32_16x16x32_bf16(af, bfv, acc[mt], 0, 0, 0);
            }
        }
        // kss = 2: lr channels (c 64..66) carried by q==0 lanes only
        bf16x8 bf2 = {0, 0, 0, 0, 0, 0, 0, 0};
        if (q == 0 && vld) {
            f32x4 L = *(const f32x4*)(lb_ + ((size_t)ii << 2));
#pragma unroll
            for (int j = 0; j < 4; j++) bf2[j] = (short)f2bf(L[j]);
        }
#pragma unroll
        for (int mt = 0; mt < 2; mt++) {
            bf16x8 af = *(const bf16x8*)(ab + (size_t)(2 * 2 + mt) * 512);
            acc[mt] = __builtin_amdgcn_mfma_f32_16x16x32_bf16(af, bf2, acc[mt], 0, 0, 0);
        }
    }

    // epilogue: D[row=q*4+r][col=n]; packed omp[(b*HW+hw)*9+tap] = {oy,ox,m,_}
    float* base = omp + ((size_t)b * HW + hw) * 36;
#pragma unroll
    for (int mt = 0; mt < 2; mt++) {
#pragma unroll
        for (int r = 0; r < 4; r++) {
            int o = mt * 16 + q * 4 + r;
            float v = acc[mt][r];
            if (o < 18) {
                int tap = o >> 1, slot = o & 1;
                base[tap * 4 + slot] = v + ob[o];
            } else if (o < 27) {
                int tap = o - 18;
                base[tap * 4 + 2] = 2.f * fast_sigmoid(v + mb[tap]);
            }
        }
    }
}

// ---------------------------------------------------------------------------
// Deformable conv as fused implicit GEMM over PIXEL-MAJOR bf16 xcat,
// split-K x2, tap loop FULLY UNROLLED (independent load chains). Block =
// 256 thr = 32 px strip; wave = (N-tile nt2) x (K-half kh: taps 0-4 / 5-8).
// Per tap: one dwordx4 packed (offy,offx,m); 4 corner rows; ks 0/1 -> four
// 16B bf16x8 corner loads, dword-wise bf16->f32 expand, fp32 bilinear
// combine, repack; ks 2 -> q==0 lanes bilinear of lrp float4s. 4 MFMAs/ks.
// kh=1 partials via LDS, single barrier. bf16 row stores. XCD swizzle.
// ---------------------------------------------------------------------------
__global__ __launch_bounds__(256, 4) void k_deform(const unsigned short* __restrict__ xcat,
                                                   const float* __restrict__ lrp,
                                                   const float* __restrict__ omp,
                                                   const unsigned short* __restrict__ apk,
                                                   const float* __restrict__ bias,
                                                   unsigned short* __restrict__ xout) {
    __shared__ float red[2 * 64 * 17];  // 8704 B
    int tid = threadIdx.x;
    int lane = tid & 63;
    int wid = __builtin_amdgcn_readfirstlane(tid >> 6);
    int nt2 = wid & 1, kh = wid >> 1;
    int blk = blockIdx.x;                    // 0..2047
    int sg = (blk & 7) * 256 + (blk >> 3);   // XCD-contiguous strip id
    int b = sg >> 9;
    int hwbase = (sg & 511) * 32;
    int n = lane & 15, q = lane >> 4;
    int hw = hwbase + nt2 * 16 + n;
    int y = hw >> 7, x = hw & (W - 1);

    f32x4 acc[4];
#pragma unroll
    for (int mt = 0; mt < 4; mt++) { f32x4 z = {0.f, 0.f, 0.f, 0.f}; acc[mt] = z; }

    const unsigned short* xb = xcat + (size_t)b * HW * CST;
    const float* lb_ = lrp + (size_t)b * HW * 4;
    const f32x4* ompx = (const f32x4*)(omp + ((size_t)b * HW + hw) * 36);
    int t0 = kh ? 5 : 0, t1 = kh ? 9 : 5;
#pragma unroll
    for (int tap = 0; tap < K2; tap++) {
        if (tap < t0 || tap >= t1) continue;
        f32x4 om = ompx[tap];
        int ky = tap / 3, kx = tap - ky * 3;
        float py = (float)(y + ky - 1) + om[0];
        float px_ = (float)(x + kx - 1) + om[1];
        float m = om[2];
        float fy = floorf(py), fx = floorf(px_);
        float wy = py - fy, wx = px_ - fx;
        int y0 = (int)fy, x0 = (int)fx;
        int y1 = y0 + 1, x1 = x0 + 1;
        float vy0 = (y0 >= 0 && y0 <= H - 1) ? 1.f : 0.f;
        float vy1 = (y1 >= 0 && y1 <= H - 1) ? 1.f : 0.f;
        float vx0 = (x0 >= 0 && x0 <= W - 1) ? 1.f : 0.f;
        float vx1 = (x1 >= 0 && x1 <= W - 1) ? 1.f : 0.f;
        int yc0 = min(max(y0, 0), H - 1), yc1 = min(max(y1, 0), H - 1);
        int xc0 = min(max(x0, 0), W - 1), xc1 = min(max(x1, 0), W - 1);
        float a00 = (1.f - wy) * (1.f - wx) * m * vy0 * vx0;
        float a01 = (1.f - wy) * wx * m * vy0 * vx1;
        float a10 = wy * (1.f - wx) * m * vy1 * vx0;
        float a11 = wy * wx * m * vy1 * vx1;
        int j00 = yc0 * W + xc0, j01 = yc0 * W + xc1;
        int j10 = yc1 * W + xc0, j11 = yc1 * W + xc1;

        const unsigned short* r00 = xb + ((size_t)j00 << 6);
        const unsigned short* r01 = xb + ((size_t)j01 << 6);
        const unsigned short* r10 = xb + ((size_t)j10 << 6);
        const unsigned short* r11 = xb + ((size_t)j11 << 6);
        const unsigned short* ab = apk + (size_t)(tap * 12) * 512 + lane * 8;
#pragma unroll
        for (int ks = 0; ks < 2; ks++) {
            int c0 = ks * 32 + q * 8;
            u32x4 d00 = *(const u32x4*)(r00 + c0);
            u32x4 d01 = *(const u32x4*)(r01 + c0);
            u32x4 d10 = *(const u32x4*)(r10 + c0);
            u32x4 d11 = *(const u32x4*)(r11 + c0);
            bf16x8 bf;
            unsigned int* bfu = (unsigned int*)&bf;
#pragma unroll
            for (int e = 0; e < 4; e++) {
                float lo = a00 * __uint_as_float(d00[e] << 16) + a01 * __uint_as_float(d01[e] << 16)
                         + a10 * __uint_as_float(d10[e] << 16) + a11 * __uint_as_float(d11[e] << 16);
                float hi = a00 * __uint_as_float(d00[e] & 0xffff0000u) + a01 * __uint_as_float(d01[e] & 0xffff0000u)
                         + a10 * __uint_as_float(d10[e] & 0xffff0000u) + a11 * __uint_as_float(d11[e] & 0xffff0000u);
                bfu[e] = (unsigned int)f2bf(lo) | ((unsigned int)f2bf(hi) << 16);
            }
#pragma unroll
            for (int mt = 0; mt < 4; mt++) {
                bf16x8 af = *(const bf16x8*)(ab + (size_t)(ks * 4 + mt) * 512);
                acc[mt] = __builtin_amdgcn_mfma_f32_16x16x32_bf16(af, bf, acc[mt], 0, 0, 0);
            }
        }
        // ks = 2: lr channels via q==0 lanes (c 64..67; rest zero, A zero too)
        bf16x8 bf2 = {0, 0, 0, 0, 0, 0, 0, 0};
        if (q == 0) {
            f32x4 L00 = *(const f32x4*)(lb_ + ((size_t)j00 << 2));
            f32x4 L01 = *(const f32x4*)(lb_ + ((size_t)j01 << 2));
            f32x4 L10 = *(const f32x4*)(lb_ + ((size_t)j10 << 2));
            f32x4 L11 = *(const f32x4*)(lb_ + ((size_t)j11 << 2));
#pragma unroll
            for (int j = 0; j < 4; j++) {
                float v = a00 * L00[j] + a01 * L01[j] + a10 * L10[j] + a11 * L11[j];
                bf2[j] = (short)f2bf(v);
            }
        }
#pragma unroll
        for (int mt = 0; mt < 4; mt++) {
            bf16x8 af = *(const bf16x8*)(ab + (size_t)(2 * 4 + mt) * 512);
            acc[mt] = __builtin_amdgcn_mfma_f32_16x16x32_bf16(af, bf2, acc[mt], 0, 0, 0);
        }
    }

    // split-K reduction: kh=1 waves stage partials, kh=0 waves add + store
    if (kh) {
#pragma unroll
        for (int mt = 0; mt < 4; mt++) {
#pragma unroll
            for (int r = 0; r < 4; r++) {
                int o = mt * 16 + q * 4 + r;
                red[(nt2 * 64 + o) * 17 + n] = acc[mt][r];
            }
        }
    }
    __syncthreads();
    if (!kh) {
        unsigned short* xo = xout + ((size_t)b * HW + hw) * CST;
#pragma unroll
        for (int mt = 0; mt < 4; mt++) {
            float s[4];
#pragma unroll
            for (int r = 0; r < 4; r++) {
                int o = mt * 16 + q * 4 + r;
                s[r] = acc[mt][r] + red[(nt2 * 64 + o) * 17 + n] + bias[o];
            }
            u32x2 st;
            st[0] = (unsigned int)f2bf(s[0]) | ((unsigned int)f2bf(s[1]) << 16);
            st[1] = (unsigned int)f2bf(s[2]) | ((unsigned int)f2bf(s[3]) << 16);
            *(u32x2*)(xo + mt * 16 + q * 4) = st;
        }
    }
}

// final 3-channel conv over pixel-major bf16 xcat (64 ch) + lrp (3 ch)
__global__ __launch_bounds__(256) void k_conv3(const unsigned short* __restrict__ xcat,
                                               const float* __restrict__ lrp,
                                               const float* __restrict__ cw,
                                               const float* __restrict__ cb,
                                               float* __restrict__ y3) {
    int t = blockIdx.x * blockDim.x + threadIdx.x;
    int b = t >> 14, hw = t & (HW - 1), y = hw >> 7, x = hw & (W - 1);
    float acc[NC] = {cb[0], cb[1], cb[2]};
    const unsigned short* xb = xcat + (size_t)b * HW * CST;
    const float* lb_ = lrp + (size_t)b * HW * 4;
#pragma unroll
    for (int tap = 0; tap < K2; tap++) {
        int ky = tap / 3, kx = tap - ky * 3;
        int yy = y + ky - 1, xx = x + kx - 1;
        if (yy < 0 || yy >= H || xx < 0 || xx >= W) continue;
        int ii = yy * W + xx;
        const unsigned short* xr = xb + ((size_t)ii << 6);
#pragma unroll
        for (int c8 = 0; c8 < 8; c8++) {
            u32x4 d = *(const u32x4*)(xr + c8 * 8);
#pragma unroll
            for (int e = 0; e < 4; e++) {
                int c = c8 * 8 + e * 2;
                float lo = __uint_as_float(d[e] << 16);
                float hi = __uint_as_float(d[e] & 0xffff0000u);
#pragma unroll
                for (int oc = 0; oc < NC; oc++) {
                    acc[oc] += lo * cw[(size_t)oc * (CIN * 9) + c * 9 + tap]
                             + hi * cw[(size_t)oc * (CIN * 9) + (c + 1) * 9 + tap];
                }
            }
        }
        f32x4 L = *(const f32x4*)(lb_ + ((size_t)ii << 2));
#pragma unroll
        for (int e = 0; e < 3; e++)
#pragma unroll
            for (int oc = 0; oc < NC; oc++)
                acc[oc] += L[e] * cw[(size_t)oc * (CIN * 9) + (64 + e) * 9 + tap];
    }
#pragma unroll
    for (int oc = 0; oc < NC; oc++) y3[(b * NC + oc) * HW + hw] = acc[oc];
}

// global average pool: one block per (b,c)
__global__ __launch_bounds__(256) void k_pool(const float* __restrict__ y3,
                                              float* __restrict__ pooled) {
    int bc = blockIdx.x;  // 0..11
    const float* p = y3 + (size_t)bc * HW;
    float s = 0.f;
    for (int i = threadIdx.x; i < HW; i += 256) s += p[i];
    __shared__ float red[256];
    red[threadIdx.x] = s;
    __syncthreads();
    for (int off = 128; off > 0; off >>= 1) {
        if (threadIdx.x < off) red[threadIdx.x] += red[threadIdx.x + off];
        __syncthreads();
    }
    if (threadIdx.x == 0) pooled[bc] = red[0] / (float)HW;
}

// tiny per-branch channel MLP -> ch[b,s,c,k]
__global__ void k_ch(const float* __restrict__ pooled, const float* __restrict__ w1,
                     const float* __restrict__ b1, const float* __restrict__ w2,
                     const float* __restrict__ b2, float* __restrict__ chbuf) {
    int t = threadIdx.x;
    if (t >= B * S2) return;
    int b = t >> 4, s = t & 15;
    float h1[MID];
#pragma unroll
    for (int m = 0; m < MID; m++) {
        float a = b1[s * MID + m];
#pragma unroll
        for (int c = 0; c < NC; c++) a += pooled[b * NC + c] * w1[(s * MID + m) * NC + c];
        h1[m] = fmaxf(a, 0.f);
    }
    for (int kk = 0; kk < NC * K2; kk++) {
        float a = b2[s * (NC * K2) + kk];
#pragma unroll
        for (int m = 0; m < MID; m++) a += h1[m] * w2[(s * (NC * K2) + kk) * MID + m];
        chbuf[(b * S2 + s) * (NC * K2) + kk] = a;
    }
}

// ---------------------------------------------------------------------------
// Fused DDF upsample: spatial-filter conv + dynamic combine + pixel_shuffle
// + clip. blockIdx.y selects 4 of the 16 branches; that quarter of sp_w/sp_b
// and ch staged in LDS (block is single-batch).
// ---------------------------------------------------------------------------
__global__ __launch_bounds__(256) void k_ddf(const float* __restrict__ y3,
                                             const float* __restrict__ spw,
                                             const float* __restrict__ spb,
                                             const float* __restrict__ chbuf,
                                             float* __restrict__ out) {
    __shared__ float s_spw[4 * K2 * NC * 9];  // 972
    __shared__ float s_spb[4 * K2];           // 36
    __shared__ float s_ch[4 * NC * K2];       // 108
    int t = blockIdx.x * blockDim.x + threadIdx.x;
    int b = t >> 14, hw = t & (HW - 1), y = hw >> 7, x = hw & (W - 1);
    int s0 = blockIdx.y * 4;
    for (int i = threadIdx.x; i < 4 * K2 * NC * 9; i += 256) s_spw[i] = spw[s0 * K2 * NC * 9 + i];
    if (threadIdx.x < 4 * K2) s_spb[threadIdx.x] = spb[s0 * K2 + threadIdx.x];
    if (threadIdx.x < 4 * NC * K2) s_ch[threadIdx.x] = chbuf[b * (S2 * NC * K2) + s0 * NC * K2 + threadIdx.x];
    __syncthreads();
    float p[NC][9];
#pragma unroll
    for (int c = 0; c < NC; c++) load_patch(y3 + (b * NC + c) * HW, y, x, p[c]);
#pragma unroll
    for (int si = 0; si < 4; si++) {
        int s = s0 + si;
        float spv[K2];
#pragma unroll
        for (int k = 0; k < K2; k++) {
            float a = s_spb[si * K2 + k];
            const float* w = s_spw + (si * K2 + k) * (NC * 9);
#pragma unroll
            for (int c = 0; c < NC; c++)
#pragma unroll
                for (int tt = 0; tt < 9; tt++) a += p[c][tt] * w[c * 9 + tt];
            spv[k] = a;
        }
        int sy = s >> 2, sx = s & 3;
#pragma unroll
        for (int c = 0; c < NC; c++) {
            float a = 0.f;
            const float* chp = s_ch + (si * NC + c) * K2;
#pragma unroll
            for (int k = 0; k < K2; k++) a += p[c][k] * (chp[k] + spv[k]);
            a = fminf(fmaxf(a, 0.f), 255.f);
            out[((size_t)(b * NC + c) * OUT_HW + (y * SCALE + sy)) * OUT_HW + (x * SCALE + sx)] = a;
        }
    }
}

extern "C" void kernel_launch(void* const* d_in, const int* in_sizes, int n_in,
                              void* d_out, int out_size, void* d_ws, size_t ws_size,
                              hipStream_t stream) {
    const float* X = (const float*)d_in[0];
    const float* lstm_w = (const float*)d_in[1];
    const float* lstm_b = (const float*)d_in[2];
    const float* ow[3] = {(const float*)d_in[3], (const float*)d_in[9], (const float*)d_in[15]};
    const float* ob[3] = {(const float*)d_in[4], (const float*)d_in[10], (const float*)d_in[16]};
    const float* mw[3] = {(const float*)d_in[5], (const float*)d_in[11], (const float*)d_in[17]};
    const float* mb[3] = {(const float*)d_in[6], (const float*)d_in[12], (const float*)d_in[18]};
    const float* dw[3] = {(const float*)d_in[7], (const float*)d_in[13], (const float*)d_in[19]};
    const float* db[3] = {(const float*)d_in[8], (const float*)d_in[14], (const float*)d_in[20]};
    const float* conv_w = (const float*)d_in[21];
    const float* conv_b = (const float*)d_in[22];
    const float* sp_w = (const float*)d_in[23];
    const float* sp_b = (const float*)d_in[24];
    const float* ch_w1 = (const float*)d_in[25];
    const float* ch_b1 = (const float*)d_in[26];
    const float* ch_w2 = (const float*)d_in[27];
    const float* ch_b2 = (const float*)d_in[28];

    float* out = (float*)d_out;
    const size_t OUT_IMG = (size_t)B * NC * OUT_HW * OUT_HW;  // 3145728
    const size_t HIDSZ = (size_t)B * NK * HW;                 // 4194304
    float* hid_out = out + OUT_IMG;
    float* cell_out = out + OUT_IMG + HIDSZ;

    float* ws = (float*)d_ws;
    const size_t XCATF = (size_t)B * HW * CST / 2;  // bf16 xcat, in float units
    unsigned short* xcatA = (unsigned short*)ws;  ws += XCATF;
    unsigned short* xcatB = (unsigned short*)ws;  ws += XCATF;
    float* lrp = ws;              ws += (size_t)B * HW * 4;
    float* omp = ws;              ws += (size_t)B * HW * 36;   // packed off/mask
    unsigned short* apk[3];
    for (int i = 0; i < 3; i++) { apk[i] = (unsigned short*)ws; ws += 108 * 512 / 2; }
    unsigned short* apkOM[3];
    for (int i = 0; i < 3; i++) { apkOM[i] = (unsigned short*)ws; ws += 54 * 512 / 2; }
    float* y3 = ws;               ws += (size_t)B * NC * HW;
    float* pooled = ws;           ws += 16;
    float* chbuf = ws;            ws += (size_t)B * S2 * NC * K2;

    dim3 blk(256);
    dim3 g1(B * HW / 256);        // 256 blocks
    dim3 g4(B * HW / 256, 4);
    dim3 gd(B * HW / 64);         // 1024 strips (offmask)
    dim3 gd2(B * HW / 32);        // 2048 strips (split-K deform)

    k_lstm<<<g4, blk, 0, stream>>>(X, lstm_w, lstm_b, xcatA, hid_out, cell_out);
    k_lr<<<g1, blk, 0, stream>>>(X, lrp);
    for (int i = 0; i < 3; i++) {
        k_prepA<<<dim3(108), dim3(512), 0, stream>>>(dw[i], apk[i]);
        k_prepOM<<<dim3(54), dim3(512), 0, stream>>>(ow[i], mw[i], apkOM[i]);
    }

    // layer 1: xcatA -> xcatB
    k_offmask<<<gd, blk, 0, stream>>>(xcatA, lrp, apkOM[0], ob[0], mb[0], omp);
    k_deform<<<gd2, blk, 0, stream>>>(xcatA, lrp, omp, apk[0], db[0], xcatB);
    // layer 2: xcatB -> xcatA
    k_offmask<<<gd, blk, 0, stream>>>(xcatB, lrp, apkOM[1], ob[1], mb[1], omp);
    k_deform<<<gd2, blk, 0, stream>>>(xcatB, lrp, omp, apk[1], db[1], xcatA);
    // layer 3: xcatA -> xcatB
    k_offmask<<<gd, blk, 0, stream>>>(xcatA, lrp, apkOM[2], ob[2], mb[2], omp);
    k_deform<<<gd2, blk, 0, stream>>>(xcatA, lrp, omp, apk[2], db[2], xcatB);

    k_conv3<<<g1, blk, 0, stream>>>(xcatB, lrp, conv_w, conv_b, y3);
    k_pool<<<dim3(B * NC), blk, 0, stream>>>(y3, pooled);
    k_ch<<<dim3(1), dim3(64), 0, stream>>>(pooled, ch_w1, ch_b1, ch_w2, ch_b2, chbuf);
    k_ddf<<<g4, blk, 0, stream>>>(y3, sp_w, sp_b, chbuf, out);
}

// Round 14
// 430.998 us; speedup vs baseline: 1.4779x; 1.1973x over previous
//
#include <hip/hip_runtime.h>
#include <hip/hip_bf16.h>
#include <math.h>

// Problem constants
#define NC 3
#define NK 64
#define KK 3
#define K2 9
#define PAD 1
#define SCALE 4
#define S2 16
#define MID 4
#define B 4
#define H 128
#define W 128
#define HW (H*W)          // 16384
#define CIN 67            // NK + NC
#define OUT_HW (H*SCALE)  // 512
#define CST 64            // pixel-major xcat row: 64 bf16 (128 B)

typedef short bf16x8 __attribute__((ext_vector_type(8)));
typedef float f32x4 __attribute__((ext_vector_type(4)));
typedef unsigned int u32x4 __attribute__((ext_vector_type(4)));
typedef unsigned int u32x2 __attribute__((ext_vector_type(2)));

__device__ __forceinline__ float fast_sigmoid(float v) { return 1.f / (1.f + __expf(-v)); }
__device__ __forceinline__ float fast_tanh(float v) { return 2.f / (1.f + __expf(-2.f * v)) - 1.f; }

// fp32 -> bf16 round-to-nearest-even
__device__ __forceinline__ unsigned short f2bf(float f) {
    unsigned int u = __float_as_uint(f);
    unsigned int r = (u + 0x7FFFu + ((u >> 16) & 1u)) >> 16;
    return (unsigned short)r;
}

// load a zero-padded 3x3 patch of one channel plane (HxW) at (y,x)
__device__ __forceinline__ void load_patch(const float* __restrict__ xc, int y, int x, float* p) {
#pragma unroll
    for (int dy = -1; dy <= 1; dy++) {
#pragma unroll
        for (int dx = -1; dx <= 1; dx++) {
            int yy = y + dy, xx = x + dx;
            float v = (yy >= 0 && yy < H && xx >= 0 && xx < W) ? xc[yy * W + xx] : 0.f;
            p[(dy + 1) * 3 + (dx + 1)] = v;
        }
    }
}

// ---------------------------------------------------------------------------
// Prepack LSTM weights into M=192 A-fragments (12 M-tiles), bf16.
// Row o: gate = o>>6 (0->i, 1->o, 2->g; lw row base {0,2NK,3NK}), nk = o&63.
// k = c*9 + tap (c<3, tap<9, k<27; 27..31 zero). grid 12 x 512.
// ---------------------------------------------------------------------------
__global__ void k_prepL(const float* __restrict__ lw, unsigned short* __restrict__ aplk) {
    int g = blockIdx.x;            // M-tile 0..11
    int tid = threadIdx.x;         // 0..511
    int lane = tid >> 3, j = tid & 7;
    int o = g * 16 + (lane & 15);
    int k = ((lane >> 4) << 3) + j;
    float val = 0.f;
    if (k < 27) {
        int c = k / 9, tap = k % 9;
        int gate = o >> 6, nk = o & 63;
        int base = (gate == 0) ? 0 : (gate == 1) ? 2 * NK : 3 * NK;
        val = lw[(size_t)(base + nk) * (CIN * 9) + c * 9 + tap];
    }
    aplk[(size_t)g * 512 + tid] = f2bf(val);
}

// ---------------------------------------------------------------------------
// ConvLSTM as MFMA implicit GEMM (h=0,c=0: only 3 X-channels, f-gate dead).
// Block = 256 thr = 4 waves = 64 px strip; wave nt owns 16 px. One K=32 step:
// lane builds B-frag from 8 patch samples (k=c*9+tap), 12 MFMAs (M=192).
// Epilogue: lane holds gi/go/gg for same nk in acc[mt],acc[mt+4],acc[mt+8];
// computes cv,hv; stores hid/cell (channel-major fp32 d_out) and xcatA
// (pixel-major bf16, 4-consecutive-channel u32x2 stores). XCD swizzle.
// ---------------------------------------------------------------------------
__global__ __launch_bounds__(256, 4) void k_lstm(const float* __restrict__ X,
                                                 const unsigned short* __restrict__ aplk,
                                                 const float* __restrict__ lb,
                                                 unsigned short* __restrict__ xcatA,
                                                 float* __restrict__ hid_out,
                                                 float* __restrict__ cell_out) {
    int tid = threadIdx.x;
    int lane = tid & 63;
    int nt = __builtin_amdgcn_readfirstlane(tid >> 6);
    int blk = blockIdx.x;
    int sg = (blk & 7) * 128 + (blk >> 3);
    int b = sg >> 8;
    int hwbase = (sg & 255) * 64;
    int n = lane & 15, q = lane >> 4;
    int hw = hwbase + nt * 16 + n;
    int y = hw >> 7, x = hw & (W - 1);

    // B-fragment: 8 patch samples, k = q*8+j
    bf16x8 bf;
#pragma unroll
    for (int j = 0; j < 8; j++) {
        int k = q * 8 + j;
        float v = 0.f;
        if (k < 27) {
            int c = k / 9, tap = k % 9;
            int ky = tap / 3, kx = tap % 3;
            int yy = y + ky - 1, xx = x + kx - 1;
            if (yy >= 0 && yy < H && xx >= 0 && xx < W)
                v = X[(size_t)(b * NC + c) * HW + yy * W + xx];
        }
        bf[j] = (short)f2bf(v);
    }

    f32x4 acc[12];
#pragma unroll
    for (int mt = 0; mt < 12; mt++) { f32x4 z = {0.f, 0.f, 0.f, 0.f}; acc[mt] = z; }
#pragma unroll
    for (int mt = 0; mt < 12; mt++) {
        bf16x8 af = *(const bf16x8*)(aplk + (size_t)mt * 512 + lane * 8);
        acc[mt] = __builtin_amdgcn_mfma_f32_16x16x32_bf16(af, bf, acc[mt], 0, 0, 0);
    }

    unsigned short* xo = xcatA + ((size_t)b * HW + hw) * CST;
#pragma unroll
    for (int mt = 0; mt < 4; mt++) {
        float hv4[4];
#pragma unroll
        for (int r = 0; r < 4; r++) {
            int nk = mt * 16 + q * 4 + r;
            float gi = acc[mt][r] + lb[nk];
            float go = acc[mt + 4][r] + lb[2 * NK + nk];
            float gg = acc[mt + 8][r] + lb[3 * NK + nk];
            float cv = fast_sigmoid(gi) * fast_tanh(gg);
            float hv = fast_sigmoid(go) * fast_tanh(cv);
            hv4[r] = hv;
            hid_out[(size_t)(b * NK + nk) * HW + hw] = hv;
            cell_out[(size_t)(b * NK + nk) * HW + hw] = cv;
        }
        u32x2 st;
        st[0] = (unsigned int)f2bf(hv4[0]) | ((unsigned int)f2bf(hv4[1]) << 16);
        st[1] = (unsigned int)f2bf(hv4[2]) | ((unsigned int)f2bf(hv4[3]) << 16);
        *(u32x2*)(xo + mt * 16 + q * 4) = st;
    }
}

// lr channels pixel-major: lrp[(b*HW+hw)*4] = {X0, X1, X2, 0}
__global__ __launch_bounds__(256) void k_lr(const float* __restrict__ X,
                                            float* __restrict__ lrp) {
    int t = blockIdx.x * blockDim.x + threadIdx.x;
    int b = t >> 14, hw = t & (HW - 1);
    f32x4 v = {X[(b * NC + 0) * HW + hw], X[(b * NC + 1) * HW + hw],
               X[(b * NC + 2) * HW + hw], 0.f};
    *(f32x4*)(lrp + ((size_t)b * HW + hw) * 4) = v;
}

// ---------------------------------------------------------------------------
// Prepack deform weights dw[o<64][c<67][k<9] into MFMA A-fragment order, bf16.
// ---------------------------------------------------------------------------
__global__ void k_prepA(const float* __restrict__ w, unsigned short* __restrict__ apk) {
    int g = blockIdx.x;            // (tap*3+ks)*4+mt
    int tid = threadIdx.x;         // 0..511
    int lane = tid >> 3, j = tid & 7;
    int mt = g & 3, r = g >> 2;    // r = tap*3+ks
    int ks = r % 3, tap = r / 3;
    int o = mt * 16 + (lane & 15);
    int c = ks * 32 + ((lane >> 4) << 3) + j;
    float val = (c < CIN) ? w[(size_t)o * (CIN * 9) + c * 9 + tap] : 0.f;
    apk[(size_t)g * 512 + tid] = f2bf(val);
}

// Prepack offset(18)+mask(9) conv weights into M=32 A-fragments, bf16.
__global__ void k_prepOM(const float* __restrict__ ow, const float* __restrict__ mw,
                         unsigned short* __restrict__ apk) {
    int g = blockIdx.x;            // (tap*3+kss)*2+mt
    int tid = threadIdx.x;         // 0..511
    int lane = tid >> 3, j = tid & 7;
    int mt = g & 1, r = g >> 1;    // r = tap*3+kss
    int kss = r % 3, tap = r / 3;
    int o = mt * 16 + (lane & 15);
    int c = kss * 32 + ((lane >> 4) << 3) + j;
    float val = 0.f;
    if (c < CIN) {
        if (o < 18) val = ow[(size_t)o * (CIN * 9) + c * 9 + tap];
        else if (o < 27) val = mw[(size_t)(o - 18) * (CIN * 9) + c * 9 + tap];
    }
    apk[(size_t)g * 512 + tid] = f2bf(val);
}

// ---------------------------------------------------------------------------
// Offset + mask convs as MFMA implicit GEMM over PIXEL-MAJOR bf16 xcat.
// ---------------------------------------------------------------------------
__global__ __launch_bounds__(256, 4) void k_offmask(const unsigned short* __restrict__ xcat,
                                                    const float* __restrict__ lrp,
                                                    const unsigned short* __restrict__ apk,
                                                    const float* __restrict__ ob,
                                                    const float* __restrict__ mb,
                                                    float* __restrict__ omp) {
    int tid = threadIdx.x;
    int lane = tid & 63;
    int nt = __builtin_amdgcn_readfirstlane(tid >> 6);
    int blk = blockIdx.x;
    int sg = (blk & 7) * 128 + (blk >> 3);  // XCD-contiguous strip id
    int b = sg >> 8;
    int hwbase = (sg & 255) * 64;
    int n = lane & 15, q = lane >> 4;
    int hw = hwbase + nt * 16 + n;
    int y = hw >> 7, x = hw & (W - 1);

    f32x4 acc[2];
#pragma unroll
    for (int mt = 0; mt < 2; mt++) { f32x4 z = {0.f, 0.f, 0.f, 0.f}; acc[mt] = z; }

    const unsigned short* xb = xcat + (size_t)b * HW * CST;
    const float* lb_ = lrp + (size_t)b * HW * 4;
#pragma unroll
    for (int tap = 0; tap < K2; tap++) {
        int ky = tap / 3, kx = tap - ky * 3;
        int yy = y + ky - 1, xx = x + kx - 1;
        bool vld = (yy >= 0 && yy < H && xx >= 0 && xx < W);
        int ii = min(max(yy, 0), H - 1) * W + min(max(xx, 0), W - 1);
        const unsigned short* xr = xb + ((size_t)ii << 6);
        const unsigned short* ab = apk + (size_t)(tap * 6) * 512 + lane * 8;
#pragma unroll
        for (int kss = 0; kss < 2; kss++) {
            bf16x8 bfv = *(const bf16x8*)(xr + kss * 32 + q * 8);
            if (!vld) { bf16x8 z = {0, 0, 0, 0, 0, 0, 0, 0}; bfv = z; }
#pragma unroll
            for (int mt = 0; mt < 2; mt++) {
                bf16x8 af = *(const bf16x8*)(ab + (size_t)(kss * 2 + mt) * 512);
                acc[mt] = __builtin_amdgcn_mfma_f32_16x16x32_bf16(af, bfv, acc[mt], 0, 0, 0);
            }
        }
        // kss = 2: lr channels (c 64..66) carried by q==0 lanes only
        bf16x8 bf2 = {0, 0, 0, 0, 0, 0, 0, 0};
        if (q == 0 && vld) {
            f32x4 L = *(const f32x4*)(lb_ + ((size_t)ii << 2));
#pragma unroll
            for (int j = 0; j < 4; j++) bf2[j] = (short)f2bf(L[j]);
        }
#pragma unroll
        for (int mt = 0; mt < 2; mt++) {
            bf16x8 af = *(const bf16x8*)(ab + (size_t)(2 * 2 + mt) * 512);
            acc[mt] = __builtin_amdgcn_mfma_f32_16x16x32_bf16(af, bf2, acc[mt], 0, 0, 0);
        }
    }

    // epilogue: packed omp[(b*HW+hw)*9+tap] = {oy,ox,m,_}
    float* base = omp + ((size_t)b * HW + hw) * 36;
#pragma unroll
    for (int mt = 0; mt < 2; mt++) {
#pragma unroll
        for (int r = 0; r < 4; r++) {
            int o = mt * 16 + q * 4 + r;
            float v = acc[mt][r];
            if (o < 18) {
                int tap = o >> 1, slot = o & 1;
                base[tap * 4 + slot] = v + ob[o];
            } else if (o < 27) {
                int tap = o - 18;
                base[tap * 4 + 2] = 2.f * fast_sigmoid(v + mb[tap]);
            }
        }
    }
}

// ---------------------------------------------------------------------------
// Deformable conv as fused implicit GEMM over PIXEL-MAJOR bf16 xcat,
// split-K x2, tap loop fully unrolled. (Round-13 structure, unchanged.)
// ---------------------------------------------------------------------------
__global__ __launch_bounds__(256, 4) void k_deform(const unsigned short* __restrict__ xcat,
                                                   const float* __restrict__ lrp,
                                                   const float* __restrict__ omp,
                                                   const unsigned short* __restrict__ apk,
                                                   const float* __restrict__ bias,
                                                   unsigned short* __restrict__ xout) {
    __shared__ float red[2 * 64 * 17];  // 8704 B
    int tid = threadIdx.x;
    int lane = tid & 63;
    int wid = __builtin_amdgcn_readfirstlane(tid >> 6);
    int nt2 = wid & 1, kh = wid >> 1;
    int blk = blockIdx.x;                    // 0..2047
    int sg = (blk & 7) * 256 + (blk >> 3);   // XCD-contiguous strip id
    int b = sg >> 9;
    int hwbase = (sg & 511) * 32;
    int n = lane & 15, q = lane >> 4;
    int hw = hwbase + nt2 * 16 + n;
    int y = hw >> 7, x = hw & (W - 1);

    f32x4 acc[4];
#pragma unroll
    for (int mt = 0; mt < 4; mt++) { f32x4 z = {0.f, 0.f, 0.f, 0.f}; acc[mt] = z; }

    const unsigned short* xb = xcat + (size_t)b * HW * CST;
    const float* lb_ = lrp + (size_t)b * HW * 4;
    const f32x4* ompx = (const f32x4*)(omp + ((size_t)b * HW + hw) * 36);
    int t0 = kh ? 5 : 0, t1 = kh ? 9 : 5;
#pragma unroll
    for (int tap = 0; tap < K2; tap++) {
        if (tap < t0 || tap >= t1) continue;
        f32x4 om = ompx[tap];
        int ky = tap / 3, kx = tap - ky * 3;
        float py = (float)(y + ky - 1) + om[0];
        float px_ = (float)(x + kx - 1) + om[1];
        float m = om[2];
        float fy = floorf(py), fx = floorf(px_);
        float wy = py - fy, wx = px_ - fx;
        int y0 = (int)fy, x0 = (int)fx;
        int y1 = y0 + 1, x1 = x0 + 1;
        float vy0 = (y0 >= 0 && y0 <= H - 1) ? 1.f : 0.f;
        float vy1 = (y1 >= 0 && y1 <= H - 1) ? 1.f : 0.f;
        float vx0 = (x0 >= 0 && x0 <= W - 1) ? 1.f : 0.f;
        float vx1 = (x1 >= 0 && x1 <= W - 1) ? 1.f : 0.f;
        int yc0 = min(max(y0, 0), H - 1), yc1 = min(max(y1, 0), H - 1);
        int xc0 = min(max(x0, 0), W - 1), xc1 = min(max(x1, 0), W - 1);
        float a00 = (1.f - wy) * (1.f - wx) * m * vy0 * vx0;
        float a01 = (1.f - wy) * wx * m * vy0 * vx1;
        float a10 = wy * (1.f - wx) * m * vy1 * vx0;
        float a11 = wy * wx * m * vy1 * vx1;
        int j00 = yc0 * W + xc0, j01 = yc0 * W + xc1;
        int j10 = yc1 * W + xc0, j11 = yc1 * W + xc1;

        const unsigned short* r00 = xb + ((size_t)j00 << 6);
        const unsigned short* r01 = xb + ((size_t)j01 << 6);
        const unsigned short* r10 = xb + ((size_t)j10 << 6);
        const unsigned short* r11 = xb + ((size_t)j11 << 6);
        const unsigned short* ab = apk + (size_t)(tap * 12) * 512 + lane * 8;
#pragma unroll
        for (int ks = 0; ks < 2; ks++) {
            int c0 = ks * 32 + q * 8;
            u32x4 d00 = *(const u32x4*)(r00 + c0);
            u32x4 d01 = *(const u32x4*)(r01 + c0);
            u32x4 d10 = *(const u32x4*)(r10 + c0);
            u32x4 d11 = *(const u32x4*)(r11 + c0);
            bf16x8 bf;
            unsigned int* bfu = (unsigned int*)&bf;
#pragma unroll
            for (int e = 0; e < 4; e++) {
                float lo = a00 * __uint_as_float(d00[e] << 16) + a01 * __uint_as_float(d01[e] << 16)
                         + a10 * __uint_as_float(d10[e] << 16) + a11 * __uint_as_float(d11[e] << 16);
                float hi = a00 * __uint_as_float(d00[e] & 0xffff0000u) + a01 * __uint_as_float(d01[e] & 0xffff0000u)
                         + a10 * __uint_as_float(d10[e] & 0xffff0000u) + a11 * __uint_as_float(d11[e] & 0xffff0000u);
                bfu[e] = (unsigned int)f2bf(lo) | ((unsigned int)f2bf(hi) << 16);
            }
#pragma unroll
            for (int mt = 0; mt < 4; mt++) {
                bf16x8 af = *(const bf16x8*)(ab + (size_t)(ks * 4 + mt) * 512);
                acc[mt] = __builtin_amdgcn_mfma_f32_16x16x32_bf16(af, bf, acc[mt], 0, 0, 0);
            }
        }
        // ks = 2: lr channels via q==0 lanes
        bf16x8 bf2 = {0, 0, 0, 0, 0, 0, 0, 0};
        if (q == 0) {
            f32x4 L00 = *(const f32x4*)(lb_ + ((size_t)j00 << 2));
            f32x4 L01 = *(const f32x4*)(lb_ + ((size_t)j01 << 2));
            f32x4 L10 = *(const f32x4*)(lb_ + ((size_t)j10 << 2));
            f32x4 L11 = *(const f32x4*)(lb_ + ((size_t)j11 << 2));
#pragma unroll
            for (int j = 0; j < 4; j++) {
                float v = a00 * L00[j] + a01 * L01[j] + a10 * L10[j] + a11 * L11[j];
                bf2[j] = (short)f2bf(v);
            }
        }
#pragma unroll
        for (int mt = 0; mt < 4; mt++) {
            bf16x8 af = *(const bf16x8*)(ab + (size_t)(2 * 4 + mt) * 512);
            acc[mt] = __builtin_amdgcn_mfma_f32_16x16x32_bf16(af, bf2, acc[mt], 0, 0, 0);
        }
    }

    // split-K reduction
    if (kh) {
#pragma unroll
        for (int mt = 0; mt < 4; mt++) {
#pragma unroll
            for (int r = 0; r < 4; r++) {
                int o = mt * 16 + q * 4 + r;
                red[(nt2 * 64 + o) * 17 + n] = acc[mt][r];
            }
        }
    }
    __syncthreads();
    if (!kh) {
        unsigned short* xo = xout + ((size_t)b * HW + hw) * CST;
#pragma unroll
        for (int mt = 0; mt < 4; mt++) {
            float s[4];
#pragma unroll
            for (int r = 0; r < 4; r++) {
                int o = mt * 16 + q * 4 + r;
                s[r] = acc[mt][r] + red[(nt2 * 64 + o) * 17 + n] + bias[o];
            }
            u32x2 st;
            st[0] = (unsigned int)f2bf(s[0]) | ((unsigned int)f2bf(s[1]) << 16);
            st[1] = (unsigned int)f2bf(s[2]) | ((unsigned int)f2bf(s[3]) << 16);
            *(u32x2*)(xo + mt * 16 + q * 4) = st;
        }
    }
}

// ---------------------------------------------------------------------------
// Final 3-channel conv, tap-split across 4 waves (taps {0-2},{3-4},{5-6},
// {7-8}) with LDS reduction: grid 1024 blocks -> 4 waves/SIMD (was 256
// blocks / 10% occupancy). Scalar state only (no indexed arrays).
// ---------------------------------------------------------------------------
__global__ __launch_bounds__(256, 4) void k_conv3(const unsigned short* __restrict__ xcat,
                                                  const float* __restrict__ lrp,
                                                  const float* __restrict__ cw,
                                                  const float* __restrict__ cb,
                                                  float* __restrict__ y3) {
    __shared__ float red[4 * 3 * 64];  // 3072 B
    int tid = threadIdx.x;
    int lane = tid & 63;
    int wid = __builtin_amdgcn_readfirstlane(tid >> 6);
    int blk = blockIdx.x;
    int sg = (blk & 7) * 128 + (blk >> 3);
    int b = sg >> 8;
    int hwbase = (sg & 255) * 64;
    int hw = hwbase + lane;
    int y = hw >> 7, x = hw & (W - 1);
    int t0 = (wid == 0) ? 0 : 3 + (wid - 1) * 2;
    int t1 = (wid == 0) ? 3 : t0 + 2;

    float a0 = 0.f, a1 = 0.f, a2 = 0.f;
    const unsigned short* xb = xcat + (size_t)b * HW * CST;
    const float* lb_ = lrp + (size_t)b * HW * 4;
#pragma unroll 1
    for (int tap = t0; tap < t1; tap++) {
        int ky = tap / 3, kx = tap - ky * 3;
        int yy = y + ky - 1, xx = x + kx - 1;
        if (yy < 0 || yy >= H || xx < 0 || xx >= W) continue;
        int ii = yy * W + xx;
        const unsigned short* xr = xb + ((size_t)ii << 6);
#pragma unroll
        for (int c8 = 0; c8 < 8; c8++) {
            u32x4 d = *(const u32x4*)(xr + c8 * 8);
#pragma unroll
            for (int e = 0; e < 4; e++) {
                int c = c8 * 8 + e * 2;
                float lo = __uint_as_float(d[e] << 16);
                float hi = __uint_as_float(d[e] & 0xffff0000u);
                a0 += lo * cw[0 * (CIN * 9) + c * 9 + tap] + hi * cw[0 * (CIN * 9) + (c + 1) * 9 + tap];
                a1 += lo * cw[1 * (CIN * 9) + c * 9 + tap] + hi * cw[1 * (CIN * 9) + (c + 1) * 9 + tap];
                a2 += lo * cw[2 * (CIN * 9) + c * 9 + tap] + hi * cw[2 * (CIN * 9) + (c + 1) * 9 + tap];
            }
        }
        f32x4 L = *(const f32x4*)(lb_ + ((size_t)ii << 2));
#pragma unroll
        for (int e = 0; e < 3; e++) {
            a0 += L[e] * cw[0 * (CIN * 9) + (64 + e) * 9 + tap];
            a1 += L[e] * cw[1 * (CIN * 9) + (64 + e) * 9 + tap];
            a2 += L[e] * cw[2 * (CIN * 9) + (64 + e) * 9 + tap];
        }
    }
    red[(wid * 3 + 0) * 64 + lane] = a0;
    red[(wid * 3 + 1) * 64 + lane] = a1;
    red[(wid * 3 + 2) * 64 + lane] = a2;
    __syncthreads();
    if (tid < 192) {
        int oc = tid >> 6, px = tid & 63;
        float s = red[(0 * 3 + oc) * 64 + px] + red[(1 * 3 + oc) * 64 + px]
                + red[(2 * 3 + oc) * 64 + px] + red[(3 * 3 + oc) * 64 + px];
        y3[(size_t)(b * NC + oc) * HW + hwbase + px] = s + cb[oc];
    }
}

// global average pool: one block per (b,c)
__global__ __launch_bounds__(256) void k_pool(const float* __restrict__ y3,
                                              float* __restrict__ pooled) {
    int bc = blockIdx.x;  // 0..11
    const float* p = y3 + (size_t)bc * HW;
    float s = 0.f;
    for (int i = threadIdx.x; i < HW; i += 256) s += p[i];
    __shared__ float red[256];
    red[threadIdx.x] = s;
    __syncthreads();
    for (int off = 128; off > 0; off >>= 1) {
        if (threadIdx.x < off) red[threadIdx.x] += red[threadIdx.x + off];
        __syncthreads();
    }
    if (threadIdx.x == 0) pooled[bc] = red[0] / (float)HW;
}

// tiny per-branch channel MLP -> ch[b,s,c,k]
__global__ void k_ch(const float* __restrict__ pooled, const float* __restrict__ w1,
                     const float* __restrict__ b1, const float* __restrict__ w2,
                     const float* __restrict__ b2, float* __restrict__ chbuf) {
    int t = threadIdx.x;
    if (t >= B * S2) return;
    int b = t >> 4, s = t & 15;
    float h1[MID];
#pragma unroll
    for (int m = 0; m < MID; m++) {
        float a = b1[s * MID + m];
#pragma unroll
        for (int c = 0; c < NC; c++) a += pooled[b * NC + c] * w1[(s * MID + m) * NC + c];
        h1[m] = fmaxf(a, 0.f);
    }
    for (int kk = 0; kk < NC * K2; kk++) {
        float a = b2[s * (NC * K2) + kk];
#pragma unroll
        for (int m = 0; m < MID; m++) a += h1[m] * w2[(s * (NC * K2) + kk) * MID + m];
        chbuf[(b * S2 + s) * (NC * K2) + kk] = a;
    }
}

// ---------------------------------------------------------------------------
// Fused DDF upsample (unchanged): spatial conv + dynamic combine +
// pixel_shuffle + clip. blockIdx.y = 4-branch group.
// ---------------------------------------------------------------------------
__global__ __launch_bounds__(256) void k_ddf(const float* __restrict__ y3,
                                             const float* __restrict__ spw,
                                             const float* __restrict__ spb,
                                             const float* __restrict__ chbuf,
                                             float* __restrict__ out) {
    __shared__ float s_spw[4 * K2 * NC * 9];  // 972
    __shared__ float s_spb[4 * K2];           // 36
    __shared__ float s_ch[4 * NC * K2];       // 108
    int t = blockIdx.x * blockDim.x + threadIdx.x;
    int b = t >> 14, hw = t & (HW - 1), y = hw >> 7, x = hw & (W - 1);
    int s0 = blockIdx.y * 4;
    for (int i = threadIdx.x; i < 4 * K2 * NC * 9; i += 256) s_spw[i] = spw[s0 * K2 * NC * 9 + i];
    if (threadIdx.x < 4 * K2) s_spb[threadIdx.x] = spb[s0 * K2 + threadIdx.x];
    if (threadIdx.x < 4 * NC * K2) s_ch[threadIdx.x] = chbuf[b * (S2 * NC * K2) + s0 * NC * K2 + threadIdx.x];
    __syncthreads();
    float p[NC][9];
#pragma unroll
    for (int c = 0; c < NC; c++) load_patch(y3 + (b * NC + c) * HW, y, x, p[c]);
#pragma unroll
    for (int si = 0; si < 4; si++) {
        int s = s0 + si;
        float spv[K2];
#pragma unroll
        for (int k = 0; k < K2; k++) {
            float a = s_spb[si * K2 + k];
            const float* w = s_spw + (si * K2 + k) * (NC * 9);
#pragma unroll
            for (int c = 0; c < NC; c++)
#pragma unroll
                for (int tt = 0; tt < 9; tt++) a += p[c][tt] * w[c * 9 + tt];
            spv[k] = a;
        }
        int sy = s >> 2, sx = s & 3;
#pragma unroll
        for (int c = 0; c < NC; c++) {
            float a = 0.f;
            const float* chp = s_ch + (si * NC + c) * K2;
#pragma unroll
            for (int k = 0; k < K2; k++) a += p[c][k] * (chp[k] + spv[k]);
            a = fminf(fmaxf(a, 0.f), 255.f);
            out[((size_t)(b * NC + c) * OUT_HW + (y * SCALE + sy)) * OUT_HW + (x * SCALE + sx)] = a;
        }
    }
}

extern "C" void kernel_launch(void* const* d_in, const int* in_sizes, int n_in,
                              void* d_out, int out_size, void* d_ws, size_t ws_size,
                              hipStream_t stream) {
    const float* X = (const float*)d_in[0];
    const float* lstm_w = (const float*)d_in[1];
    const float* lstm_b = (const float*)d_in[2];
    const float* ow[3] = {(const float*)d_in[3], (const float*)d_in[9], (const float*)d_in[15]};
    const float* ob[3] = {(const float*)d_in[4], (const float*)d_in[10], (const float*)d_in[16]};
    const float* mw[3] = {(const float*)d_in[5], (const float*)d_in[11], (const float*)d_in[17]};
    const float* mb[3] = {(const float*)d_in[6], (const float*)d_in[12], (const float*)d_in[18]};
    const float* dw[3] = {(const float*)d_in[7], (const float*)d_in[13], (const float*)d_in[19]};
    const float* db[3] = {(const float*)d_in[8], (const float*)d_in[14], (const float*)d_in[20]};
    const float* conv_w = (const float*)d_in[21];
    const float* conv_b = (const float*)d_in[22];
    const float* sp_w = (const float*)d_in[23];
    const float* sp_b = (const float*)d_in[24];
    const float* ch_w1 = (const float*)d_in[25];
    const float* ch_b1 = (const float*)d_in[26];
    const float* ch_w2 = (const float*)d_in[27];
    const float* ch_b2 = (const float*)d_in[28];

    float* out = (float*)d_out;
    const size_t OUT_IMG = (size_t)B * NC * OUT_HW * OUT_HW;  // 3145728
    const size_t HIDSZ = (size_t)B * NK * HW;                 // 4194304
    float* hid_out = out + OUT_IMG;
    float* cell_out = out + OUT_IMG + HIDSZ;

    float* ws = (float*)d_ws;
    const size_t XCATF = (size_t)B * HW * CST / 2;  // bf16 xcat, in float units
    unsigned short* xcatA = (unsigned short*)ws;  ws += XCATF;
    unsigned short* xcatB = (unsigned short*)ws;  ws += XCATF;
    float* lrp = ws;              ws += (size_t)B * HW * 4;
    float* omp = ws;              ws += (size_t)B * HW * 36;   // packed off/mask
    unsigned short* apk[3];
    for (int i = 0; i < 3; i++) { apk[i] = (unsigned short*)ws; ws += 108 * 512 / 2; }
    unsigned short* apkOM[3];
    for (int i = 0; i < 3; i++) { apkOM[i] = (unsigned short*)ws; ws += 54 * 512 / 2; }
    unsigned short* aplk = (unsigned short*)ws;  ws += 12 * 512 / 2;
    float* y3 = ws;               ws += (size_t)B * NC * HW;
    float* pooled = ws;           ws += 16;
    float* chbuf = ws;            ws += (size_t)B * S2 * NC * K2;

    dim3 blk(256);
    dim3 g1(B * HW / 256);        // 256 blocks
    dim3 g4(B * HW / 256, 4);
    dim3 gd(B * HW / 64);         // 1024 strips
    dim3 gd2(B * HW / 32);        // 2048 strips (split-K deform)

    k_prepL<<<dim3(12), dim3(512), 0, stream>>>(lstm_w, aplk);
    for (int i = 0; i < 3; i++) {
        k_prepA<<<dim3(108), dim3(512), 0, stream>>>(dw[i], apk[i]);
        k_prepOM<<<dim3(54), dim3(512), 0, stream>>>(ow[i], mw[i], apkOM[i]);
    }
    k_lstm<<<gd, blk, 0, stream>>>(X, aplk, lstm_b, xcatA, hid_out, cell_out);
    k_lr<<<g1, blk, 0, stream>>>(X, lrp);

    // layer 1: xcatA -> xcatB
    k_offmask<<<gd, blk, 0, stream>>>(xcatA, lrp, apkOM[0], ob[0], mb[0], omp);
    k_deform<<<gd2, blk, 0, stream>>>(xcatA, lrp, omp, apk[0], db[0], xcatB);
    // layer 2: xcatB -> xcatA
    k_offmask<<<gd, blk, 0, stream>>>(xcatB, lrp, apkOM[1], ob[1], mb[1], omp);
    k_deform<<<gd2, blk, 0, stream>>>(xcatB, lrp, omp, apk[1], db[1], xcatA);
    // layer 3: xcatA -> xcatB
    k_offmask<<<gd, blk, 0, stream>>>(xcatA, lrp, apkOM[2], ob[2], mb[2], omp);
    k_deform<<<gd2, blk, 0, stream>>>(xcatA, lrp, omp, apk[2], db[2], xcatB);

    k_conv3<<<gd, blk, 0, stream>>>(xcatB, lrp, conv_w, conv_b, y3);
    k_pool<<<dim3(B * NC), blk, 0, stream>>>(y3, pooled);
    k_ch<<<dim3(1), dim3(64), 0, stream>>>(pooled, ch_w1, ch_b1, ch_w2, ch_b2, chbuf);
    k_ddf<<<g4, blk, 0, stream>>>(y3, sp_w, sp_b, chbuf, out);
}